// Round 4
// baseline (10445.651 us; speedup 1.0000x reference)
//
#include <hip/hip_runtime.h>
#include <hip/hip_bf16.h>
#include <math.h>

// ---------------- model dims ----------------
constexpr long TOK  = 32768;            // B*N*T
constexpr long HALF = TOK * 768;
constexpr int FLAG_ACC = 1, FLAG_GELU = 2, FLAG_PERM = 4, FLAG_BF16 = 8;

typedef __bf16 bf16x8 __attribute__((ext_vector_type(8)));
typedef float  f32x4  __attribute__((ext_vector_type(4)));

__device__ __forceinline__ void gload_lds16(const void* g, void* l) {
    __builtin_amdgcn_global_load_lds(
        (const __attribute__((address_space(1))) void*)g,
        (__attribute__((address_space(3))) void*)l, 16, 0, 0);
}
__device__ __forceinline__ float bf2f(__hip_bfloat16 v) { return __bfloat162float(v); }

// ---------------- bf16 MFMA GEMM (128x128 tile, XCD-swizzled) ----------------
__global__ __launch_bounds__(256) void gemm_bf16(
    const __hip_bfloat16* __restrict__ A,
    const __hip_bfloat16* __restrict__ BT,
    const float* __restrict__ bias,
    void* __restrict__ Cv, int ldc,
    int M, int N, int K, int flags, int moff)
{
    __shared__ __hip_bfloat16 As[128 * 32];
    __shared__ __hip_bfloat16 Bs[128 * 32];
    const int tid = threadIdx.x;
    const int wv = tid >> 6, lane = tid & 63;
    // bijective XCD swizzle (m204)
    const int nwg = gridDim.x * gridDim.y;
    const int orig = blockIdx.y * gridDim.x + blockIdx.x;
    const int q8 = nwg >> 3, r8 = nwg & 7;
    const int xcd = orig & 7, off = orig >> 3;
    const int wgid = (xcd < r8 ? xcd * (q8 + 1) : r8 * (q8 + 1) + (xcd - r8) * q8) + off;
    const int bm = (wgid / gridDim.x) * 128, bn = (wgid % gridDim.x) * 128;
    const int wr = (wv >> 1) * 64, wc = (wv & 1) * 64;
    const int lrow = lane & 15, lk = lane >> 4;
    const int ck = (lk ^ (lrow & 3)) * 8;

    f32x4 acc[4][4];
#pragma unroll
    for (int m = 0; m < 4; m++)
#pragma unroll
        for (int n = 0; n < 4; n++) acc[m][n] = f32x4{0.f, 0.f, 0.f, 0.f};

    for (int k0 = 0; k0 < K; k0 += 32) {
#pragma unroll
        for (int i = 0; i < 2; i++) {
            const int lin = i * 256 + tid;
            const int row = lin >> 2;
            const int ks  = (((lin & 3) ^ (row & 3)) * 8);
            const long asrc = (long)(bm + row) * K + k0 + ks;
            const long bsrc = (long)(bn + row) * K + k0 + ks;
            char* la = (char*)As + (i * 256 + wv * 64) * 16;
            char* lb = (char*)Bs + (i * 256 + wv * 64) * 16;
            gload_lds16(A + asrc, la);
            gload_lds16(BT + bsrc, lb);
        }
        __syncthreads();
        bf16x8 af[4], bfr[4];
#pragma unroll
        for (int m = 0; m < 4; m++) {
            af[m]  = *(const bf16x8*)(const void*)&As[(wr + m * 16 + lrow) * 32 + ck];
            bfr[m] = *(const bf16x8*)(const void*)&Bs[(wc + m * 16 + lrow) * 32 + ck];
        }
#pragma unroll
        for (int m = 0; m < 4; m++)
#pragma unroll
            for (int n = 0; n < 4; n++)
                acc[m][n] = __builtin_amdgcn_mfma_f32_16x16x32_bf16(af[m], bfr[n], acc[m][n], 0, 0, 0);
        __syncthreads();
    }

    float* Cf = (float*)Cv;
    __hip_bfloat16* Cb = (__hip_bfloat16*)Cv;
#pragma unroll
    for (int m = 0; m < 4; m++) {
        const int gr = bm + wr + m * 16 + lk * 4;
#pragma unroll
        for (int n = 0; n < 4; n++) {
            const int gc = bn + wc + n * 16 + lrow;
            if (gc >= N) continue;
            const float bv = bias ? bias[gc] : 0.f;
#pragma unroll
            for (int j = 0; j < 4; j++) {
                float v = acc[m][n][j] + bv;
                const int grow = gr + j;
                if (flags & FLAG_GELU) {
                    float x = v;
                    float t = tanhf(0.7978845608028654f * (x + 0.044715f * x * x * x));
                    v = 0.5f * x * (1.0f + t);
                }
                if (flags & FLAG_PERM) {
                    const int mg = moff + grow;
                    const int b_ = mg >> 13, t_ = (mg >> 7) & 63, n_ = mg & 127;
                    Cf[(((long)(b_ * 128 + n_)) * 64 + t_) * ldc + gc] = v;
                } else if (flags & FLAG_BF16) {
                    Cb[(long)grow * ldc + gc] = __float2bfloat16(v);
                } else if (flags & FLAG_ACC) {
                    Cf[(long)grow * ldc + gc] += v;
                } else {
                    Cf[(long)grow * ldc + gc] = v;
                }
            }
        }
    }
}

// ---------------- weight transpose-convert: W (KxN f32) -> WT (Npad x K bf16) ----
__global__ void convT_kernel(const float* __restrict__ W, __hip_bfloat16* __restrict__ WT,
                             int K, int N, int Npad)
{
    __shared__ float t[32][33];
    const int k0 = blockIdx.y * 32, n0 = blockIdx.x * 32;
    const int tx = threadIdx.x & 31, ty = threadIdx.x >> 5;
#pragma unroll
    for (int i = 0; i < 4; i++) {
        int k = k0 + ty + i * 8, n = n0 + tx;
        t[ty + i * 8][tx] = (k < K && n < N) ? W[(long)k * N + n] : 0.f;
    }
    __syncthreads();
#pragma unroll
    for (int i = 0; i < 4; i++) {
        int n = n0 + ty + i * 8, k = k0 + tx;
        if (n < Npad && k < K) WT[(long)n * K + k] = __float2bfloat16(t[tx][ty + i * 8]);
    }
}

// ---------------- f32 -> bf16 elementwise ----------------
__global__ void cvt_kernel(const float4* __restrict__ x, ushort4* __restrict__ y, long n4)
{
    long i = (long)blockIdx.x * 256 + threadIdx.x;
    if (i >= n4) return;
    float4 v = x[i];
    __hip_bfloat16 a = __float2bfloat16(v.x), b = __float2bfloat16(v.y);
    __hip_bfloat16 c = __float2bfloat16(v.z), d = __float2bfloat16(v.w);
    ushort4 o = { *(ushort*)&a, *(ushort*)&b, *(ushort*)&c, *(ushort*)&d };
    y[i] = o;
}

// ---------------- RMSNorm, wave-per-row (f32 / bf16 input) ----------------
__global__ void rmsnorm_f32(const float* __restrict__ x, const float* __restrict__ w,
                            __hip_bfloat16* __restrict__ out, int D, int xs, int os, long nrows)
{
    const int wv = threadIdx.x >> 6, lane = threadIdx.x & 63;
    const long row = (long)blockIdx.x * 4 + wv;
    if (row >= nrows) return;
    const float* xr = x + row * xs;
    float ss = 0.f;
    for (int i = lane; i < D; i += 64) { float v = xr[i]; ss += v * v; }
    for (int o = 32; o; o >>= 1) ss += __shfl_xor(ss, o);
    const float sc = rsqrtf(ss / D + 1e-5f);
    __hip_bfloat16* orow = out + row * os;
    for (int i = lane; i < D; i += 64) orow[i] = __float2bfloat16(xr[i] * sc * w[i]);
}
__global__ void rmsnorm_b16(const __hip_bfloat16* __restrict__ x, const float* __restrict__ w,
                            __hip_bfloat16* __restrict__ out, int D, int xs, int os, long nrows)
{
    const int wv = threadIdx.x >> 6, lane = threadIdx.x & 63;
    const long row = (long)blockIdx.x * 4 + wv;
    if (row >= nrows) return;
    const __hip_bfloat16* xr = x + row * xs;
    float ss = 0.f;
    for (int i = lane; i < D; i += 64) { float v = bf2f(xr[i]); ss += v * v; }
    for (int o = 32; o; o >>= 1) ss += __shfl_xor(ss, o);
    const float sc = rsqrtf(ss / D + 1e-5f);
    __hip_bfloat16* orow = out + row * os;
    for (int i = lane; i < D; i += 64) orow[i] = __float2bfloat16(bf2f(xr[i]) * sc * w[i]);
}

// ---------------- fused attention: per (batch, head), float4 LDS ----------------
__global__ __launch_bounds__(256) void attn_kernel(
    const __hip_bfloat16* __restrict__ QKV, __hip_bfloat16* __restrict__ O)
{
    __shared__ float Qs[64 * 100];   // later overlaid by Ps (64x65)
    __shared__ float Ks[64 * 100];   // later overlaid by Vs (64x100)
    const int b = blockIdx.x >> 3, h = blockIdx.x & 7;
    const int tid = threadIdx.x;
    const long base = (long)b * 64 * 2304 + h * 96;
    for (int i = tid; i < 6144; i += 256) {
        int t = i / 96, d = i - t * 96;
        Qs[t * 100 + d] = bf2f(QKV[base + (long)t * 2304 + d]);
        int g = ((d >> 2) ^ ((t >> 4) & 3)) << 2;
        Ks[t * 100 + g + (d & 3)] = bf2f(QKV[base + (long)t * 2304 + 768 + d]);
    }
    __syncthreads();
    const int i_ = tid >> 2, j0 = (tid & 3) << 4;
    float sv[16];
#pragma unroll
    for (int jj = 0; jj < 16; jj++) sv[jj] = 0.f;
    for (int d0 = 0; d0 < 96; d0 += 4) {
        const float4 q4 = *(const float4*)&Qs[i_ * 100 + d0];
#pragma unroll
        for (int jj = 0; jj < 16; jj++) {
            const int r = j0 + jj;
            const int g = (((d0 >> 2) ^ ((r >> 4) & 3)) << 2);
            const float4 k4 = *(const float4*)&Ks[r * 100 + g];
            sv[jj] += q4.x * k4.x + q4.y * k4.y + q4.z * k4.z + q4.w * k4.w;
        }
    }
    const float scale = 0.102062072615966f;   // 1/sqrt(96)
    float mx = sv[0] * scale;
#pragma unroll
    for (int jj = 0; jj < 16; jj++) { sv[jj] *= scale; mx = fmaxf(mx, sv[jj]); }
    mx = fmaxf(mx, __shfl_xor(mx, 1));
    mx = fmaxf(mx, __shfl_xor(mx, 2));
    float sum = 0.f;
#pragma unroll
    for (int jj = 0; jj < 16; jj++) { sv[jj] = expf(sv[jj] - mx); sum += sv[jj]; }
    sum += __shfl_xor(sum, 1);
    sum += __shfl_xor(sum, 2);
    const float inv = 1.f / sum;
    __syncthreads();
    float* Ps = Qs;                  // 64 x 65
#pragma unroll
    for (int jj = 0; jj < 16; jj++) Ps[i_ * 65 + j0 + jj] = sv[jj] * inv;
    float* Vs = Ks;                  // 64 x 100
    for (int i = tid; i < 6144; i += 256) {
        int t = i / 96, d = i - t * 96;
        Vs[t * 100 + d] = bf2f(QKV[base + (long)t * 2304 + 1536 + d]);
    }
    __syncthreads();
    const int t_ = tid & 63, dg = (tid >> 6) * 24;
    float o4[24];
#pragma unroll
    for (int c = 0; c < 24; c++) o4[c] = 0.f;
    for (int k = 0; k < 64; k++) {
        const float p = Ps[t_ * 65 + k];
#pragma unroll
        for (int c = 0; c < 6; c++) {
            const float4 v4 = *(const float4*)&Vs[k * 100 + dg + c * 4];
            o4[c * 4 + 0] += p * v4.x; o4[c * 4 + 1] += p * v4.y;
            o4[c * 4 + 2] += p * v4.z; o4[c * 4 + 3] += p * v4.w;
        }
    }
    const long ob = (long)(b * 64 + t_) * 768 + h * 96 + dg;
#pragma unroll
    for (int c = 0; c < 24; c++) O[ob + c] = __float2bfloat16(o4[c]);
}

// ---------------- transpose p (B,N,T,D) -> z (B,T,N,D) ----------------
__global__ void transpose_kernel(const float* __restrict__ P, float* __restrict__ Z)
{
    long lin = (long)blockIdx.x * 256 + threadIdx.x;
    if (lin >= HALF) return;
    int d = (int)(lin % 768);
    long rowz = lin / 768;
    int n = rowz & 127, t = (int)((rowz >> 7) & 63), b = (int)(rowz >> 13);
    long rowp = ((long)(b * 128 + n)) * 64 + t;
    Z[lin] = P[rowp * 768 + d];
}

// -------- causal depthwise conv + SiLU: x-part -> bf16 xc, B/C -> f32 bcF ------
__global__ void conv_kernel(const __hip_bfloat16* __restrict__ zx,
                            const float* __restrict__ cw, const float* __restrict__ cb,
                            __hip_bfloat16* __restrict__ xc, float* __restrict__ bcF,
                            long rows)
{
    long lin = (long)blockIdx.x * 256 + threadIdx.x;
    if (lin >= rows * 1664) return;
    int c = (int)(lin % 1664);
    long r = lin / 1664;
    int n = (int)(r & 127);
    float acc = cb[c];
#pragma unroll
    for (int k = 0; k < 4; k++) {
        int nn = n - 3 + k;
        if (nn >= 0) acc += cw[k * 1664 + c] * bf2f(zx[(r - 3 + k) * 3328 + 1536 + c]);
    }
    acc = acc / (1.f + expf(-acc));
    if (c < 1536) xc[r * 1664 + c] = __float2bfloat16(acc);
    else          bcF[r * 128 + (c - 1536)] = acc;
}

// ---------------- dt = softplus(dt_raw + bias) -> f32 side buffer ----------------
__global__ void dt_kernel(const __hip_bfloat16* __restrict__ zx, const float* __restrict__ bias,
                          float* __restrict__ dtf, long count)
{
    long lin = (long)blockIdx.x * 256 + threadIdx.x;
    if (lin >= count) return;
    int h = (int)(lin % 24);
    long r = lin / 24;
    float v = bf2f(zx[r * 3328 + 3200 + h]) + bias[h];
    dtf[lin] = (v > 0.f) ? v + log1pf(expf(-v)) : log1pf(expf(v));
}

// ------- SSM scan: 1 wave per (bt, head); no LDS; B/C via uniform f32 loads -----
__global__ __launch_bounds__(64) void scan_kernel(
    const __hip_bfloat16* __restrict__ zx, const float* __restrict__ dtf,
    const float* __restrict__ bcF, __hip_bfloat16* __restrict__ xc,
    const float* __restrict__ Alog, const float* __restrict__ Dskip,
    float* __restrict__ hout, int bt0)
{
    const int btl = blockIdx.x / 24, h = blockIdx.x % 24;
    const int lane = threadIdx.x;
    const float A = -expf(Alog[h]);
    const float Dh = Dskip[h];
    f32x4 hs[16];
#pragma unroll
    for (int i = 0; i < 16; i++) hs[i] = f32x4{0.f, 0.f, 0.f, 0.f};
    const long rbase = (long)btl * 128;
#pragma unroll 2
    for (int t = 0; t < 128; t++) {
        const long r = rbase + t;
        const float x  = bf2f(xc[r * 1664 + h * 64 + lane]);
        const float dt = dtf[r * 24 + h];
        const float zg = bf2f(zx[r * 3328 + h * 64 + lane]);
        const f32x4* bc4 = (const f32x4*)(bcF + r * 128);   // wave-uniform
        const float dA = expf(dt * A);
        const float coef = dt * x;
        f32x4 acc4 = f32x4{0.f, 0.f, 0.f, 0.f};
#pragma unroll
        for (int sq = 0; sq < 16; sq++) {
            const f32x4 Bq = bc4[sq];
            const f32x4 Cq = bc4[16 + sq];
            hs[sq] = hs[sq] * dA + Bq * coef;
            acc4 += hs[sq] * Cq;
        }
        const float acc = acc4[0] + acc4[1] + acc4[2] + acc4[3];
        const float y = (acc + Dh * x) * (zg / (1.f + expf(-zg)));
        xc[r * 1664 + h * 64 + lane] = __float2bfloat16(y);
    }
    if (hout) {
        long base = ((long)(bt0 + btl) * 24 + h) * 4096 + (long)lane * 64;
#pragma unroll
        for (int sq = 0; sq < 16; sq++)
#pragma unroll
            for (int j = 0; j < 4; j++) hout[base + sq * 4 + j] = hs[sq][j];
    }
}

// ---------------- host orchestration ----------------
extern "C" void kernel_launch(void* const* d_in, const int* in_sizes, int n_in,
                              void* d_out, int out_size, void* d_ws, size_t ws_size,
                              hipStream_t stream)
{
    const float* precepts  = (const float*)d_in[0];
    const float* actions   = (const float*)d_in[1];
    const float* attn_n1   = (const float*)d_in[2];
    const float* Wq        = (const float*)d_in[3];
    const float* Wk        = (const float*)d_in[4];
    const float* Wv        = (const float*)d_in[5];
    const float* Wo        = (const float*)d_in[6];
    const float* attn_n2   = (const float*)d_in[7];
    const float* ffn_w1    = (const float*)d_in[8];
    const float* ffn_b1    = (const float*)d_in[9];
    const float* ffn_w2    = (const float*)d_in[10];
    const float* ffn_b2    = (const float*)d_in[11];
    const float* ssm_norm  = (const float*)d_in[12];
    const float* in_proj   = (const float*)d_in[13];
    const float* conv_w    = (const float*)d_in[14];
    const float* conv_b    = (const float*)d_in[15];
    const float* dt_bias   = (const float*)d_in[16];
    const float* A_log     = (const float*)d_in[17];
    const float* D_skip    = (const float*)d_in[18];
    const float* mamba_nw  = (const float*)d_in[19];
    const float* out_proj  = (const float*)d_in[20];
    const float* proj_w    = (const float*)d_in[21];
    const float* proj_b    = (const float*)d_in[22];

    float* out  = (float*)d_out;
    float* Z    = out;            // z residual in out[0:HALF], dead before final GEMM
    float* P    = out + HALF;     // attention residual, dead before h_last written
    float* hout = out + HALF;

    // ---- ws: bf16 transposed weights, then phase-union scratch ----
    __hip_bfloat16* wb = (__hip_bfloat16*)d_ws;
    long wo = 0;
    auto walloc = [&](long els) { __hip_bfloat16* p = wb + wo; wo += els; return p; };
    __hip_bfloat16* WqkvT = walloc(4L * 2304 * 768);
    __hip_bfloat16* W1T   = walloc(4L * 3072 * 768);
    __hip_bfloat16* W2T   = walloc(4L * 768 * 3072);
    __hip_bfloat16* inT   = walloc(4L * 3328 * 768);
    __hip_bfloat16* outT  = walloc(4L * 768 * 1536);
    __hip_bfloat16* projT = walloc(768L * 768);
    __hip_bfloat16* WoT   = walloc(4L * 768 * 768);
    char* pbase = (char*)(wb + ((wo + 255) & ~255L));
    const size_t used_w = (size_t)(pbase - (char*)d_ws);
    const size_t avail = ws_size > used_w ? ws_size - used_w : 0;

    int CB = 512;                 // attention chunk (batches of 64 tokens)
    while (CB > 8 && (unsigned long long)CB * 884736ull > avail) CB >>= 1;
    int CBT = 256;                // mamba chunk (sequences of 128)
    while (CBT > 2 && (unsigned long long)CBT * 1945600ull > avail) CBT >>= 1;

    auto gemm = [&](const __hip_bfloat16* A, const __hip_bfloat16* BT, const float* bias,
                    void* C, int ldc, int M, int N, int Npad, int K, int flags, int moff) {
        dim3 g(Npad / 128, M / 128);
        hipLaunchKernelGGL(gemm_bf16, g, dim3(256), 0, stream,
                           A, BT, bias, C, ldc, M, N, K, flags, moff);
    };
    auto cvtT = [&](const float* W, __hip_bfloat16* WT, int K, int N, int Npad) {
        dim3 g((Npad + 31) / 32, (K + 31) / 32);
        hipLaunchKernelGGL(convT_kernel, g, dim3(256), 0, stream, W, WT, K, N, Npad);
    };
    auto cvt = [&](const float* x, __hip_bfloat16* y, long n) {
        long n4 = n / 4;
        hipLaunchKernelGGL(cvt_kernel, dim3((n4 + 255) / 256), dim3(256), 0, stream,
                           (const float4*)x, (ushort4*)y, n4);
    };
    auto rmsF = [&](const float* x, const float* w, __hip_bfloat16* o, int D, int xs, int os, long rows) {
        hipLaunchKernelGGL(rmsnorm_f32, dim3((rows + 3) / 4), dim3(256), 0, stream,
                           x, w, o, D, xs, os, rows);
    };
    auto rmsB = [&](const __hip_bfloat16* x, const float* w, __hip_bfloat16* o, int D, int xs, int os, long rows) {
        hipLaunchKernelGGL(rmsnorm_b16, dim3((rows + 3) / 4), dim3(256), 0, stream,
                           x, w, o, D, xs, os, rows);
    };

    // ---- weight conversion ----
    for (int l = 0; l < 4; l++) {
        cvtT(Wq + (long)l * 589824, WqkvT + (long)l * 2304 * 768,                768, 768, 768);
        cvtT(Wk + (long)l * 589824, WqkvT + (long)l * 2304 * 768 +  768L * 768,  768, 768, 768);
        cvtT(Wv + (long)l * 589824, WqkvT + (long)l * 2304 * 768 + 1536L * 768,  768, 768, 768);
        cvtT(Wo + (long)l * 589824, WoT + (long)l * 589824, 768, 768, 768);
        cvtT(ffn_w1 + (long)l * 2359296, W1T + (long)l * 2359296, 768, 3072, 3072);
        cvtT(ffn_w2 + (long)l * 2359296, W2T + (long)l * 2359296, 3072, 768, 768);
    }
    for (int m = 0; m < 4; m++) {
        cvtT(in_proj + (long)m * 768 * 3224, inT + (long)m * 3328 * 768, 768, 3224, 3328);
        cvtT(out_proj + (long)m * 1536 * 768, outT + (long)m * 768 * 1536, 1536, 768, 768);
    }
    cvtT(proj_w, projT, 768, 768, 768);

    // ---- attention stack ----
    hipMemcpyAsync(P, precepts, HALF * sizeof(float), hipMemcpyDeviceToDevice, stream);
    {
        const long rA = (long)CB * 64;
        __hip_bfloat16* bufA   = (__hip_bfloat16*)pbase;        // rA x 768
        __hip_bfloat16* actB   = bufA + rA * 768;               // rA x 768
        __hip_bfloat16* bufQKV = actB + rA * 768;               // rA x 2304
        __hip_bfloat16* bufH   = bufQKV + rA * 2304;            // rA x 3072
        const int nac = 512 / CB;
        const int Mr = (int)rA;
        if (nac == 1) cvt(actions, actB, rA * 768);
        for (int layer = 0; layer < 4; layer++) {
            const bool cross = ((layer + 1) % 2) == 0;
            for (int c = 0; c < nac; c++) {
                const long tok0 = (long)c * rA;
                float* Pc = P + tok0 * 768;
                rmsF(Pc, attn_n1 + layer * 768, bufA, 768, 768, 768, Mr);
                if (!cross) {
                    gemm(bufA, WqkvT + (long)layer * 2304 * 768, nullptr, bufQKV, 2304,
                         Mr, 2304, 2304, 768, FLAG_BF16, 0);
                } else {
                    if (nac != 1) cvt(actions + tok0 * 768, actB, rA * 768);
                    gemm(bufA, WqkvT + (long)layer * 2304 * 768, nullptr, bufQKV, 2304,
                         Mr, 768, 768, 768, FLAG_BF16, 0);
                    gemm(actB, WqkvT + (long)layer * 2304 * 768 + 768L * 768, nullptr,
                         bufQKV + 768, 2304, Mr, 1536, 1536, 768, FLAG_BF16, 0);
                }
                hipLaunchKernelGGL(attn_kernel, dim3(CB * 8), dim3(256), 0, stream,
                                   bufQKV, bufA);
                gemm(bufA, WoT + (long)layer * 589824, nullptr, Pc, 768,
                     Mr, 768, 768, 768, FLAG_ACC, 0);
                rmsF(Pc, attn_n2 + layer * 768, bufA, 768, 768, 768, Mr);
                gemm(bufA, W1T + (long)layer * 2359296, ffn_b1 + layer * 3072, bufH, 3072,
                     Mr, 3072, 3072, 768, FLAG_GELU | FLAG_BF16, 0);
                gemm(bufH, W2T + (long)layer * 2359296, ffn_b2 + layer * 768, Pc, 768,
                     Mr, 768, 768, 3072, FLAG_ACC, 0);
            }
        }
    }

    // ---- transpose to SSM layout ----
    hipLaunchKernelGGL(transpose_kernel, dim3((int)((HALF + 255) / 256)), dim3(256), 0, stream, P, Z);

    // ---- mamba blocks ----
    {
        const long rM = (long)CBT * 128;
        __hip_bfloat16* xn  = (__hip_bfloat16*)pbase;            // rM x 768
        __hip_bfloat16* zx  = xn + rM * 768;                     // rM x 3328
        float*          dtf = (float*)(zx + rM * 3328);          // rM x 24
        __hip_bfloat16* xc  = (__hip_bfloat16*)(dtf + rM * 24);  // rM x 1664
        __hip_bfloat16* yb  = xc + rM * 1664;                    // rM x 1536
        float*          bcF = (float*)(yb + rM * 1536);          // rM x 128
        const int nmc = 256 / CBT;
        const int Mr = (int)rM;
        for (int m = 0; m < 4; m++) {
            for (int c = 0; c < nmc; c++) {
                float* Zc = Z + (long)c * rM * 768;
                rmsF(Zc, ssm_norm + m * 768, xn, 768, 768, 768, Mr);
                gemm(xn, inT + (long)m * 3328 * 768, nullptr, zx, 3328,
                     Mr, 3224, 3328, 768, FLAG_BF16, 0);
                const long convn = rM * 1664;
                hipLaunchKernelGGL(conv_kernel, dim3((int)((convn + 255) / 256)), dim3(256), 0, stream,
                                   zx, conv_w + m * 4 * 1664, conv_b + m * 1664, xc, bcF, rM);
                const long dtn = rM * 24;
                hipLaunchKernelGGL(dt_kernel, dim3((int)((dtn + 255) / 256)), dim3(256), 0, stream,
                                   zx, dt_bias + m * 24, dtf, dtn);
                hipLaunchKernelGGL(scan_kernel, dim3(CBT * 24), dim3(64), 0, stream,
                                   zx, dtf, bcF, xc, A_log + m * 24, D_skip + m * 24,
                                   (m == 3) ? hout : nullptr, c * CBT);
                rmsB(xc, mamba_nw + m * 1536, yb, 1536, 1664, 1536, Mr);
                gemm(yb, outT + (long)m * 768 * 1536, nullptr, Zc, 768,
                     Mr, 768, 768, 1536, FLAG_ACC, 0);
            }
        }
    }

    // ---- final projection: convert all of Z, then PERM GEMM ----
    {
        __hip_bfloat16* Zb = (__hip_bfloat16*)pbase;
        cvt(Z, Zb, HALF);
        gemm(Zb, projT, proj_b, out, 768, 32768, 768, 768, 768, FLAG_PERM, 0);
    }
}

// Round 5
// 10131.688 us; speedup vs baseline: 1.0310x; 1.0310x over previous
//
#include <hip/hip_runtime.h>
#include <hip/hip_bf16.h>
#include <math.h>

// ---------------- model dims ----------------
constexpr long TOK  = 32768;            // B*N*T
constexpr long HALF = TOK * 768;
constexpr int FLAG_ACC = 1, FLAG_GELU = 2, FLAG_PERM = 4, FLAG_BF16 = 8;

typedef __bf16 bf16x8 __attribute__((ext_vector_type(8)));
typedef float  f32x4  __attribute__((ext_vector_type(4)));

__device__ __forceinline__ void gload_lds16(const void* g, void* l) {
    __builtin_amdgcn_global_load_lds(
        (const __attribute__((address_space(1))) void*)g,
        (__attribute__((address_space(3))) void*)l, 16, 0, 0);
}
__device__ __forceinline__ float bf2f(__hip_bfloat16 v) { return __bfloat162float(v); }
__device__ __forceinline__ float rdlane(float v, int lane) {
    return __int_as_float(__builtin_amdgcn_readlane(__float_as_int(v), lane));
}

// ---------------- bf16 MFMA GEMM (128x128 tile, XCD-swizzled) ----------------
__global__ __launch_bounds__(256) void gemm_bf16(
    const __hip_bfloat16* __restrict__ A,
    const __hip_bfloat16* __restrict__ BT,
    const float* __restrict__ bias,
    void* __restrict__ Cv, int ldc,
    int M, int N, int K, int flags, int moff)
{
    __shared__ __hip_bfloat16 As[128 * 32];
    __shared__ __hip_bfloat16 Bs[128 * 32];
    const int tid = threadIdx.x;
    const int wv = tid >> 6, lane = tid & 63;
    // bijective XCD swizzle (m204)
    const int nwg = gridDim.x * gridDim.y;
    const int orig = blockIdx.y * gridDim.x + blockIdx.x;
    const int q8 = nwg >> 3, r8 = nwg & 7;
    const int xcd = orig & 7, off = orig >> 3;
    const int wgid = (xcd < r8 ? xcd * (q8 + 1) : r8 * (q8 + 1) + (xcd - r8) * q8) + off;
    const int bm = (wgid / gridDim.x) * 128, bn = (wgid % gridDim.x) * 128;
    const int wr = (wv >> 1) * 64, wc = (wv & 1) * 64;
    const int lrow = lane & 15, lk = lane >> 4;
    const int ck = (lk ^ (lrow & 3)) * 8;

    f32x4 acc[4][4];
#pragma unroll
    for (int m = 0; m < 4; m++)
#pragma unroll
        for (int n = 0; n < 4; n++) acc[m][n] = f32x4{0.f, 0.f, 0.f, 0.f};

    for (int k0 = 0; k0 < K; k0 += 32) {
#pragma unroll
        for (int i = 0; i < 2; i++) {
            const int lin = i * 256 + tid;
            const int row = lin >> 2;
            const int ks  = (((lin & 3) ^ (row & 3)) * 8);
            const long asrc = (long)(bm + row) * K + k0 + ks;
            const long bsrc = (long)(bn + row) * K + k0 + ks;
            char* la = (char*)As + (i * 256 + wv * 64) * 16;
            char* lb = (char*)Bs + (i * 256 + wv * 64) * 16;
            gload_lds16(A + asrc, la);
            gload_lds16(BT + bsrc, lb);
        }
        __syncthreads();
        bf16x8 af[4], bfr[4];
#pragma unroll
        for (int m = 0; m < 4; m++) {
            af[m]  = *(const bf16x8*)(const void*)&As[(wr + m * 16 + lrow) * 32 + ck];
            bfr[m] = *(const bf16x8*)(const void*)&Bs[(wc + m * 16 + lrow) * 32 + ck];
        }
#pragma unroll
        for (int m = 0; m < 4; m++)
#pragma unroll
            for (int n = 0; n < 4; n++)
                acc[m][n] = __builtin_amdgcn_mfma_f32_16x16x32_bf16(af[m], bfr[n], acc[m][n], 0, 0, 0);
        __syncthreads();
    }

    float* Cf = (float*)Cv;
    __hip_bfloat16* Cb = (__hip_bfloat16*)Cv;
#pragma unroll
    for (int m = 0; m < 4; m++) {
        const int gr = bm + wr + m * 16 + lk * 4;
#pragma unroll
        for (int n = 0; n < 4; n++) {
            const int gc = bn + wc + n * 16 + lrow;
            if (gc >= N) continue;
            const float bv = bias ? bias[gc] : 0.f;
#pragma unroll
            for (int j = 0; j < 4; j++) {
                float v = acc[m][n][j] + bv;
                const int grow = gr + j;
                if (flags & FLAG_GELU) {
                    float x = v;
                    float t = tanhf(0.7978845608028654f * (x + 0.044715f * x * x * x));
                    v = 0.5f * x * (1.0f + t);
                }
                if (flags & FLAG_PERM) {
                    const int mg = moff + grow;
                    const int b_ = mg >> 13, t_ = (mg >> 7) & 63, n_ = mg & 127;
                    Cf[(((long)(b_ * 128 + n_)) * 64 + t_) * ldc + gc] = v;
                } else if (flags & FLAG_BF16) {
                    Cb[(long)grow * ldc + gc] = __float2bfloat16(v);
                } else if (flags & FLAG_ACC) {
                    Cf[(long)grow * ldc + gc] += v;
                } else {
                    Cf[(long)grow * ldc + gc] = v;
                }
            }
        }
    }
}

// ---------------- weight transpose-convert: W (KxN f32) -> WT (Npad x K bf16) ----
__global__ void convT_kernel(const float* __restrict__ W, __hip_bfloat16* __restrict__ WT,
                             int K, int N, int Npad)
{
    __shared__ float t[32][33];
    const int k0 = blockIdx.y * 32, n0 = blockIdx.x * 32;
    const int tx = threadIdx.x & 31, ty = threadIdx.x >> 5;
#pragma unroll
    for (int i = 0; i < 4; i++) {
        int k = k0 + ty + i * 8, n = n0 + tx;
        t[ty + i * 8][tx] = (k < K && n < N) ? W[(long)k * N + n] : 0.f;
    }
    __syncthreads();
#pragma unroll
    for (int i = 0; i < 4; i++) {
        int n = n0 + ty + i * 8, k = k0 + tx;
        if (n < Npad && k < K) WT[(long)n * K + k] = __float2bfloat16(t[tx][ty + i * 8]);
    }
}

// ---------------- f32 -> bf16 elementwise ----------------
__global__ void cvt_kernel(const float4* __restrict__ x, ushort4* __restrict__ y, long n4)
{
    long i = (long)blockIdx.x * 256 + threadIdx.x;
    if (i >= n4) return;
    float4 v = x[i];
    __hip_bfloat16 a = __float2bfloat16(v.x), b = __float2bfloat16(v.y);
    __hip_bfloat16 c = __float2bfloat16(v.z), d = __float2bfloat16(v.w);
    ushort4 o = { *(ushort*)&a, *(ushort*)&b, *(ushort*)&c, *(ushort*)&d };
    y[i] = o;
}

// ---------------- RMSNorm, wave-per-row (f32 / bf16 input) ----------------
__global__ void rmsnorm_f32(const float* __restrict__ x, const float* __restrict__ w,
                            __hip_bfloat16* __restrict__ out, int D, int xs, int os, long nrows)
{
    const int wv = threadIdx.x >> 6, lane = threadIdx.x & 63;
    const long row = (long)blockIdx.x * 4 + wv;
    if (row >= nrows) return;
    const float* xr = x + row * xs;
    float ss = 0.f;
    for (int i = lane; i < D; i += 64) { float v = xr[i]; ss += v * v; }
    for (int o = 32; o; o >>= 1) ss += __shfl_xor(ss, o);
    const float sc = rsqrtf(ss / D + 1e-5f);
    __hip_bfloat16* orow = out + row * os;
    for (int i = lane; i < D; i += 64) orow[i] = __float2bfloat16(xr[i] * sc * w[i]);
}
__global__ void rmsnorm_b16(const __hip_bfloat16* __restrict__ x, const float* __restrict__ w,
                            __hip_bfloat16* __restrict__ out, int D, int xs, int os, long nrows)
{
    const int wv = threadIdx.x >> 6, lane = threadIdx.x & 63;
    const long row = (long)blockIdx.x * 4 + wv;
    if (row >= nrows) return;
    const __hip_bfloat16* xr = x + row * xs;
    float ss = 0.f;
    for (int i = lane; i < D; i += 64) { float v = bf2f(xr[i]); ss += v * v; }
    for (int o = 32; o; o >>= 1) ss += __shfl_xor(ss, o);
    const float sc = rsqrtf(ss / D + 1e-5f);
    __hip_bfloat16* orow = out + row * os;
    for (int i = lane; i < D; i += 64) orow[i] = __float2bfloat16(bf2f(xr[i]) * sc * w[i]);
}

// ---------------- fused attention: per (batch, head), float4 LDS ----------------
__global__ __launch_bounds__(256) void attn_kernel(
    const __hip_bfloat16* __restrict__ QKV, __hip_bfloat16* __restrict__ O)
{
    __shared__ float Qs[64 * 100];
    __shared__ float Ks[64 * 100];
    const int b = blockIdx.x >> 3, h = blockIdx.x & 7;
    const int tid = threadIdx.x;
    const long base = (long)b * 64 * 2304 + h * 96;
    for (int i = tid; i < 6144; i += 256) {
        int t = i / 96, d = i - t * 96;
        Qs[t * 100 + d] = bf2f(QKV[base + (long)t * 2304 + d]);
        int g = ((d >> 2) ^ ((t >> 4) & 3)) << 2;
        Ks[t * 100 + g + (d & 3)] = bf2f(QKV[base + (long)t * 2304 + 768 + d]);
    }
    __syncthreads();
    const int i_ = tid >> 2, j0 = (tid & 3) << 4;
    float sv[16];
#pragma unroll
    for (int jj = 0; jj < 16; jj++) sv[jj] = 0.f;
    for (int d0 = 0; d0 < 96; d0 += 4) {
        const float4 q4 = *(const float4*)&Qs[i_ * 100 + d0];
#pragma unroll
        for (int jj = 0; jj < 16; jj++) {
            const int r = j0 + jj;
            const int g = (((d0 >> 2) ^ ((r >> 4) & 3)) << 2);
            const float4 k4 = *(const float4*)&Ks[r * 100 + g];
            sv[jj] += q4.x * k4.x + q4.y * k4.y + q4.z * k4.z + q4.w * k4.w;
        }
    }
    const float scale = 0.102062072615966f;
    float mx = sv[0] * scale;
#pragma unroll
    for (int jj = 0; jj < 16; jj++) { sv[jj] *= scale; mx = fmaxf(mx, sv[jj]); }
    mx = fmaxf(mx, __shfl_xor(mx, 1));
    mx = fmaxf(mx, __shfl_xor(mx, 2));
    float sum = 0.f;
#pragma unroll
    for (int jj = 0; jj < 16; jj++) { sv[jj] = expf(sv[jj] - mx); sum += sv[jj]; }
    sum += __shfl_xor(sum, 1);
    sum += __shfl_xor(sum, 2);
    const float inv = 1.f / sum;
    __syncthreads();
    float* Ps = Qs;
#pragma unroll
    for (int jj = 0; jj < 16; jj++) Ps[i_ * 65 + j0 + jj] = sv[jj] * inv;
    float* Vs = Ks;
    for (int i = tid; i < 6144; i += 256) {
        int t = i / 96, d = i - t * 96;
        Vs[t * 100 + d] = bf2f(QKV[base + (long)t * 2304 + 1536 + d]);
    }
    __syncthreads();
    const int t_ = tid & 63, dg = (tid >> 6) * 24;
    float o4[24];
#pragma unroll
    for (int c = 0; c < 24; c++) o4[c] = 0.f;
    for (int k = 0; k < 64; k++) {
        const float p = Ps[t_ * 65 + k];
#pragma unroll
        for (int c = 0; c < 6; c++) {
            const float4 v4 = *(const float4*)&Vs[k * 100 + dg + c * 4];
            o4[c * 4 + 0] += p * v4.x; o4[c * 4 + 1] += p * v4.y;
            o4[c * 4 + 2] += p * v4.z; o4[c * 4 + 3] += p * v4.w;
        }
    }
    const long ob = (long)(b * 64 + t_) * 768 + h * 96 + dg;
#pragma unroll
    for (int c = 0; c < 24; c++) O[ob + c] = __float2bfloat16(o4[c]);
}

// ---------------- transpose p (B,N,T,D) -> z (B,T,N,D) ----------------
__global__ void transpose_kernel(const float* __restrict__ P, float* __restrict__ Z)
{
    long lin = (long)blockIdx.x * 256 + threadIdx.x;
    if (lin >= HALF) return;
    int d = (int)(lin % 768);
    long rowz = lin / 768;
    int n = rowz & 127, t = (int)((rowz >> 7) & 63), b = (int)(rowz >> 13);
    long rowp = ((long)(b * 128 + n)) * 64 + t;
    Z[lin] = P[rowp * 768 + d];
}

// -------- causal depthwise conv + SiLU: x-part -> bf16 xc, B/C -> f32 bcF ------
__global__ void conv_kernel(const __hip_bfloat16* __restrict__ zx,
                            const float* __restrict__ cw, const float* __restrict__ cb,
                            __hip_bfloat16* __restrict__ xc, float* __restrict__ bcF,
                            long rows)
{
    long lin = (long)blockIdx.x * 256 + threadIdx.x;
    if (lin >= rows * 1664) return;
    int c = (int)(lin % 1664);
    long r = lin / 1664;
    int n = (int)(r & 127);
    float acc = cb[c];
#pragma unroll
    for (int k = 0; k < 4; k++) {
        int nn = n - 3 + k;
        if (nn >= 0) acc += cw[k * 1664 + c] * bf2f(zx[(r - 3 + k) * 3328 + 1536 + c]);
    }
    acc = acc / (1.f + expf(-acc));
    if (c < 1536) xc[r * 1664 + c] = __float2bfloat16(acc);
    else          bcF[r * 128 + (c - 1536)] = acc;
}

// ---------------- dt = softplus(dt_raw + bias) -> f32 side buffer ----------------
__global__ void dt_kernel(const __hip_bfloat16* __restrict__ zx, const float* __restrict__ bias,
                          float* __restrict__ dtf, long count)
{
    long lin = (long)blockIdx.x * 256 + threadIdx.x;
    if (lin >= count) return;
    int h = (int)(lin % 24);
    long r = lin / 24;
    float v = bf2f(zx[r * 3328 + 3200 + h]) + bias[h];
    dtf[lin] = (v > 0.f) ? v + log1pf(expf(-v)) : log1pf(expf(v));
}

// ------- SSM scan: 4 waves/block (4 heads, same bt); coalesced B/C row load +
// ------- v_readlane broadcast (no LDS, no uniform VMEM); t+1 prefetch ----------
__global__ __launch_bounds__(256) void scan_kernel(
    const __hip_bfloat16* __restrict__ zx, const float* __restrict__ dtf,
    const float* __restrict__ bcF, __hip_bfloat16* __restrict__ xc,
    const float* __restrict__ Alog, const float* __restrict__ Dskip,
    float* __restrict__ hout, int bt0)
{
    const int wv = threadIdx.x >> 6, lane = threadIdx.x & 63;
    const int btl = blockIdx.x / 6;
    const int h = (blockIdx.x % 6) * 4 + wv;
    const float A = -expf(Alog[h]);
    const float Dh = Dskip[h];
    float hs[64];
#pragma unroll
    for (int s = 0; s < 64; s++) hs[s] = 0.f;
    long r = (long)btl * 128;
    // prefetch t=0
    float2 bcn = *(const float2*)(bcF + r * 128 + lane * 2);
    float xn   = bf2f(xc[r * 1664 + h * 64 + lane]);
    float dtn  = dtf[r * 24 + h];
    float zgn  = bf2f(zx[r * 3328 + h * 64 + lane]);
    for (int t = 0; t < 128; t++) {
        const float2 bc = bcn;
        const float x = xn, dt = dtn, zg = zgn;
        if (t < 127) {               // prefetch t+1 (hides all load latency)
            const long rn = r + 1;
            bcn = *(const float2*)(bcF + rn * 128 + lane * 2);
            xn  = bf2f(xc[rn * 1664 + h * 64 + lane]);
            dtn = dtf[rn * 24 + h];
            zgn = bf2f(zx[rn * 3328 + h * 64 + lane]);
        }
        const float dA = expf(dt * A);
        const float coef = dt * x;
        float acc = 0.f;
#pragma unroll
        for (int s = 0; s < 64; s++) {
            // B[s] = element s of row -> lane s/2, comp s&1 ; C[s] = element 64+s
            const float Bs = rdlane((s & 1) ? bc.y : bc.x, s >> 1);
            const float Cs = rdlane((s & 1) ? bc.y : bc.x, 32 + (s >> 1));
            hs[s] = hs[s] * dA + coef * Bs;
            acc += hs[s] * Cs;
        }
        const float y = (acc + Dh * x) * (zg / (1.f + expf(-zg)));
        xc[r * 1664 + h * 64 + lane] = __float2bfloat16(y);
        r++;
    }
    if (hout) {
        long base = ((long)(bt0 + btl) * 24 + h) * 4096 + (long)lane * 64;
#pragma unroll
        for (int s = 0; s < 64; s++) hout[base + s] = hs[s];
    }
}

// ---------------- host orchestration ----------------
extern "C" void kernel_launch(void* const* d_in, const int* in_sizes, int n_in,
                              void* d_out, int out_size, void* d_ws, size_t ws_size,
                              hipStream_t stream)
{
    const float* precepts  = (const float*)d_in[0];
    const float* actions   = (const float*)d_in[1];
    const float* attn_n1   = (const float*)d_in[2];
    const float* Wq        = (const float*)d_in[3];
    const float* Wk        = (const float*)d_in[4];
    const float* Wv        = (const float*)d_in[5];
    const float* Wo        = (const float*)d_in[6];
    const float* attn_n2   = (const float*)d_in[7];
    const float* ffn_w1    = (const float*)d_in[8];
    const float* ffn_b1    = (const float*)d_in[9];
    const float* ffn_w2    = (const float*)d_in[10];
    const float* ffn_b2    = (const float*)d_in[11];
    const float* ssm_norm  = (const float*)d_in[12];
    const float* in_proj   = (const float*)d_in[13];
    const float* conv_w    = (const float*)d_in[14];
    const float* conv_b    = (const float*)d_in[15];
    const float* dt_bias   = (const float*)d_in[16];
    const float* A_log     = (const float*)d_in[17];
    const float* D_skip    = (const float*)d_in[18];
    const float* mamba_nw  = (const float*)d_in[19];
    const float* out_proj  = (const float*)d_in[20];
    const float* proj_w    = (const float*)d_in[21];
    const float* proj_b    = (const float*)d_in[22];

    float* out  = (float*)d_out;
    float* Z    = out;            // z residual in out[0:HALF], dead before final GEMM
    float* P    = out + HALF;     // attention residual, dead before h_last written
    float* hout = out + HALF;

    // ---- ws: bf16 transposed weights, then phase-union scratch ----
    __hip_bfloat16* wb = (__hip_bfloat16*)d_ws;
    long wo = 0;
    auto walloc = [&](long els) { __hip_bfloat16* p = wb + wo; wo += els; return p; };
    __hip_bfloat16* WqkvT = walloc(4L * 2304 * 768);
    __hip_bfloat16* W1T   = walloc(4L * 3072 * 768);
    __hip_bfloat16* W2T   = walloc(4L * 768 * 3072);
    __hip_bfloat16* inT   = walloc(4L * 3328 * 768);
    __hip_bfloat16* outT  = walloc(4L * 768 * 1536);
    __hip_bfloat16* projT = walloc(768L * 768);
    __hip_bfloat16* WoT   = walloc(4L * 768 * 768);
    char* pbase = (char*)(wb + ((wo + 255) & ~255L));
    const size_t used_w = (size_t)(pbase - (char*)d_ws);
    const size_t avail = ws_size > used_w ? ws_size - used_w : 0;

    int CB = 512;                 // attention chunk (batches of 64 tokens)
    while (CB > 8 && (unsigned long long)CB * 884736ull > avail) CB >>= 1;
    int CBT = 256;                // mamba chunk (sequences of 128)
    while (CBT > 2 && (unsigned long long)CBT * 1945600ull > avail) CBT >>= 1;

    auto gemm = [&](const __hip_bfloat16* A, const __hip_bfloat16* BT, const float* bias,
                    void* C, int ldc, int M, int N, int Npad, int K, int flags, int moff) {
        dim3 g(Npad / 128, M / 128);
        hipLaunchKernelGGL(gemm_bf16, g, dim3(256), 0, stream,
                           A, BT, bias, C, ldc, M, N, K, flags, moff);
    };
    auto cvtT = [&](const float* W, __hip_bfloat16* WT, int K, int N, int Npad) {
        dim3 g((Npad + 31) / 32, (K + 31) / 32);
        hipLaunchKernelGGL(convT_kernel, g, dim3(256), 0, stream, W, WT, K, N, Npad);
    };
    auto cvt = [&](const float* x, __hip_bfloat16* y, long n) {
        long n4 = n / 4;
        hipLaunchKernelGGL(cvt_kernel, dim3((n4 + 255) / 256), dim3(256), 0, stream,
                           (const float4*)x, (ushort4*)y, n4);
    };
    auto rmsF = [&](const float* x, const float* w, __hip_bfloat16* o, int D, int xs, int os, long rows) {
        hipLaunchKernelGGL(rmsnorm_f32, dim3((rows + 3) / 4), dim3(256), 0, stream,
                           x, w, o, D, xs, os, rows);
    };
    auto rmsB = [&](const __hip_bfloat16* x, const float* w, __hip_bfloat16* o, int D, int xs, int os, long rows) {
        hipLaunchKernelGGL(rmsnorm_b16, dim3((rows + 3) / 4), dim3(256), 0, stream,
                           x, w, o, D, xs, os, rows);
    };

    // ---- weight conversion ----
    for (int l = 0; l < 4; l++) {
        cvtT(Wq + (long)l * 589824, WqkvT + (long)l * 2304 * 768,                768, 768, 768);
        cvtT(Wk + (long)l * 589824, WqkvT + (long)l * 2304 * 768 +  768L * 768,  768, 768, 768);
        cvtT(Wv + (long)l * 589824, WqkvT + (long)l * 2304 * 768 + 1536L * 768,  768, 768, 768);
        cvtT(Wo + (long)l * 589824, WoT + (long)l * 589824, 768, 768, 768);
        cvtT(ffn_w1 + (long)l * 2359296, W1T + (long)l * 2359296, 768, 3072, 3072);
        cvtT(ffn_w2 + (long)l * 2359296, W2T + (long)l * 2359296, 3072, 768, 768);
    }
    for (int m = 0; m < 4; m++) {
        cvtT(in_proj + (long)m * 768 * 3224, inT + (long)m * 3328 * 768, 768, 3224, 3328);
        cvtT(out_proj + (long)m * 1536 * 768, outT + (long)m * 768 * 1536, 1536, 768, 768);
    }
    cvtT(proj_w, projT, 768, 768, 768);

    // ---- attention stack ----
    hipMemcpyAsync(P, precepts, HALF * sizeof(float), hipMemcpyDeviceToDevice, stream);
    {
        const long rA = (long)CB * 64;
        __hip_bfloat16* bufA   = (__hip_bfloat16*)pbase;        // rA x 768
        __hip_bfloat16* actB   = bufA + rA * 768;               // rA x 768
        __hip_bfloat16* bufQKV = actB + rA * 768;               // rA x 2304
        __hip_bfloat16* bufH   = bufQKV + rA * 2304;            // rA x 3072
        const int nac = 512 / CB;
        const int Mr = (int)rA;
        if (nac == 1) cvt(actions, actB, rA * 768);
        for (int layer = 0; layer < 4; layer++) {
            const bool cross = ((layer + 1) % 2) == 0;
            for (int c = 0; c < nac; c++) {
                const long tok0 = (long)c * rA;
                float* Pc = P + tok0 * 768;
                rmsF(Pc, attn_n1 + layer * 768, bufA, 768, 768, 768, Mr);
                if (!cross) {
                    gemm(bufA, WqkvT + (long)layer * 2304 * 768, nullptr, bufQKV, 2304,
                         Mr, 2304, 2304, 768, FLAG_BF16, 0);
                } else {
                    if (nac != 1) cvt(actions + tok0 * 768, actB, rA * 768);
                    gemm(bufA, WqkvT + (long)layer * 2304 * 768, nullptr, bufQKV, 2304,
                         Mr, 768, 768, 768, FLAG_BF16, 0);
                    gemm(actB, WqkvT + (long)layer * 2304 * 768 + 768L * 768, nullptr,
                         bufQKV + 768, 2304, Mr, 1536, 1536, 768, FLAG_BF16, 0);
                }
                hipLaunchKernelGGL(attn_kernel, dim3(CB * 8), dim3(256), 0, stream,
                                   bufQKV, bufA);
                gemm(bufA, WoT + (long)layer * 589824, nullptr, Pc, 768,
                     Mr, 768, 768, 768, FLAG_ACC, 0);
                rmsF(Pc, attn_n2 + layer * 768, bufA, 768, 768, 768, Mr);
                gemm(bufA, W1T + (long)layer * 2359296, ffn_b1 + layer * 3072, bufH, 3072,
                     Mr, 3072, 3072, 768, FLAG_GELU | FLAG_BF16, 0);
                gemm(bufH, W2T + (long)layer * 2359296, ffn_b2 + layer * 768, Pc, 768,
                     Mr, 768, 768, 3072, FLAG_ACC, 0);
            }
        }
    }

    // ---- transpose to SSM layout ----
    hipLaunchKernelGGL(transpose_kernel, dim3((int)((HALF + 255) / 256)), dim3(256), 0, stream, P, Z);

    // ---- mamba blocks ----
    {
        const long rM = (long)CBT * 128;
        __hip_bfloat16* xn  = (__hip_bfloat16*)pbase;            // rM x 768
        __hip_bfloat16* zx  = xn + rM * 768;                     // rM x 3328
        float*          dtf = (float*)(zx + rM * 3328);          // rM x 24
        __hip_bfloat16* xc  = (__hip_bfloat16*)(dtf + rM * 24);  // rM x 1664
        __hip_bfloat16* yb  = xc + rM * 1664;                    // rM x 1536
        float*          bcF = (float*)(yb + rM * 1536);          // rM x 128
        const int nmc = 256 / CBT;
        const int Mr = (int)rM;
        for (int m = 0; m < 4; m++) {
            for (int c = 0; c < nmc; c++) {
                float* Zc = Z + (long)c * rM * 768;
                rmsF(Zc, ssm_norm + m * 768, xn, 768, 768, 768, Mr);
                gemm(xn, inT + (long)m * 3328 * 768, nullptr, zx, 3328,
                     Mr, 3224, 3328, 768, FLAG_BF16, 0);
                const long convn = rM * 1664;
                hipLaunchKernelGGL(conv_kernel, dim3((int)((convn + 255) / 256)), dim3(256), 0, stream,
                                   zx, conv_w + m * 4 * 1664, conv_b + m * 1664, xc, bcF, rM);
                const long dtn = rM * 24;
                hipLaunchKernelGGL(dt_kernel, dim3((int)((dtn + 255) / 256)), dim3(256), 0, stream,
                                   zx, dt_bias + m * 24, dtf, dtn);
                hipLaunchKernelGGL(scan_kernel, dim3(CBT * 6), dim3(256), 0, stream,
                                   zx, dtf, bcF, xc, A_log + m * 24, D_skip + m * 24,
                                   (m == 3) ? hout : nullptr, c * CBT);
                rmsB(xc, mamba_nw + m * 1536, yb, 1536, 1664, 1536, Mr);
                gemm(yb, outT + (long)m * 768 * 1536, nullptr, Zc, 768,
                     Mr, 768, 768, 1536, FLAG_ACC, 0);
            }
        }
    }

    // ---- final projection: convert all of Z, then PERM GEMM ----
    {
        __hip_bfloat16* Zb = (__hip_bfloat16*)pbase;
        cvt(Z, Zb, HALF);
        gemm(Zb, projT, proj_b, out, 768, 32768, 768, 768, 768, FLAG_PERM, 0);
    }
}

// Round 6
// 9107.117 us; speedup vs baseline: 1.1470x; 1.1125x over previous
//
#include <hip/hip_runtime.h>
#include <hip/hip_bf16.h>
#include <math.h>

// ---------------- model dims ----------------
constexpr long TOK  = 32768;            // B*N*T
constexpr long HALF = TOK * 768;
constexpr int FLAG_ACC = 1, FLAG_GELU = 2, FLAG_PERM = 4, FLAG_BF16 = 8;

typedef __bf16 bf16x8 __attribute__((ext_vector_type(8)));
typedef float  f32x4  __attribute__((ext_vector_type(4)));

__device__ __forceinline__ void gload_lds16(const void* g, void* l) {
    __builtin_amdgcn_global_load_lds(
        (const __attribute__((address_space(1))) void*)g,
        (__attribute__((address_space(3))) void*)l, 16, 0, 0);
}
__device__ __forceinline__ float bf2f(__hip_bfloat16 v) { return __bfloat162float(v); }

// ---------------- bf16 MFMA GEMM (128x128 tile, XCD-swizzled) ----------------
__global__ __launch_bounds__(256) void gemm_bf16(
    const __hip_bfloat16* __restrict__ A,
    const __hip_bfloat16* __restrict__ BT,
    const float* __restrict__ bias,
    void* __restrict__ Cv, int ldc,
    int M, int N, int K, int flags, int moff)
{
    __shared__ __hip_bfloat16 As[128 * 32];
    __shared__ __hip_bfloat16 Bs[128 * 32];
    const int tid = threadIdx.x;
    const int wv = tid >> 6, lane = tid & 63;
    const int nwg = gridDim.x * gridDim.y;
    const int orig = blockIdx.y * gridDim.x + blockIdx.x;
    const int q8 = nwg >> 3, r8 = nwg & 7;
    const int xcd = orig & 7, off = orig >> 3;
    const int wgid = (xcd < r8 ? xcd * (q8 + 1) : r8 * (q8 + 1) + (xcd - r8) * q8) + off;
    const int bm = (wgid / gridDim.x) * 128, bn = (wgid % gridDim.x) * 128;
    const int wr = (wv >> 1) * 64, wc = (wv & 1) * 64;
    const int lrow = lane & 15, lk = lane >> 4;
    const int ck = (lk ^ (lrow & 3)) * 8;

    f32x4 acc[4][4];
#pragma unroll
    for (int m = 0; m < 4; m++)
#pragma unroll
        for (int n = 0; n < 4; n++) acc[m][n] = f32x4{0.f, 0.f, 0.f, 0.f};

    for (int k0 = 0; k0 < K; k0 += 32) {
#pragma unroll
        for (int i = 0; i < 2; i++) {
            const int lin = i * 256 + tid;
            const int row = lin >> 2;
            const int ks  = (((lin & 3) ^ (row & 3)) * 8);
            const long asrc = (long)(bm + row) * K + k0 + ks;
            const long bsrc = (long)(bn + row) * K + k0 + ks;
            char* la = (char*)As + (i * 256 + wv * 64) * 16;
            char* lb = (char*)Bs + (i * 256 + wv * 64) * 16;
            gload_lds16(A + asrc, la);
            gload_lds16(BT + bsrc, lb);
        }
        __syncthreads();
        bf16x8 af[4], bfr[4];
#pragma unroll
        for (int m = 0; m < 4; m++) {
            af[m]  = *(const bf16x8*)(const void*)&As[(wr + m * 16 + lrow) * 32 + ck];
            bfr[m] = *(const bf16x8*)(const void*)&Bs[(wc + m * 16 + lrow) * 32 + ck];
        }
#pragma unroll
        for (int m = 0; m < 4; m++)
#pragma unroll
            for (int n = 0; n < 4; n++)
                acc[m][n] = __builtin_amdgcn_mfma_f32_16x16x32_bf16(af[m], bfr[n], acc[m][n], 0, 0, 0);
        __syncthreads();
    }

    float* Cf = (float*)Cv;
    __hip_bfloat16* Cb = (__hip_bfloat16*)Cv;
#pragma unroll
    for (int m = 0; m < 4; m++) {
        const int gr = bm + wr + m * 16 + lk * 4;
#pragma unroll
        for (int n = 0; n < 4; n++) {
            const int gc = bn + wc + n * 16 + lrow;
            if (gc >= N) continue;
            const float bv = bias ? bias[gc] : 0.f;
#pragma unroll
            for (int j = 0; j < 4; j++) {
                float v = acc[m][n][j] + bv;
                const int grow = gr + j;
                if (flags & FLAG_GELU) {
                    float x = v;
                    float t = tanhf(0.7978845608028654f * (x + 0.044715f * x * x * x));
                    v = 0.5f * x * (1.0f + t);
                }
                if (flags & FLAG_PERM) {
                    const int mg = moff + grow;
                    const int b_ = mg >> 13, t_ = (mg >> 7) & 63, n_ = mg & 127;
                    Cf[(((long)(b_ * 128 + n_)) * 64 + t_) * ldc + gc] = v;
                } else if (flags & FLAG_BF16) {
                    Cb[(long)grow * ldc + gc] = __float2bfloat16(v);
                } else if (flags & FLAG_ACC) {
                    Cf[(long)grow * ldc + gc] += v;
                } else {
                    Cf[(long)grow * ldc + gc] = v;
                }
            }
        }
    }
}

// ---------------- weight transpose-convert: W (KxN f32) -> WT (Npad x K bf16) ----
__global__ void convT_kernel(const float* __restrict__ W, __hip_bfloat16* __restrict__ WT,
                             int K, int N, int Npad)
{
    __shared__ float t[32][33];
    const int k0 = blockIdx.y * 32, n0 = blockIdx.x * 32;
    const int tx = threadIdx.x & 31, ty = threadIdx.x >> 5;
#pragma unroll
    for (int i = 0; i < 4; i++) {
        int k = k0 + ty + i * 8, n = n0 + tx;
        t[ty + i * 8][tx] = (k < K && n < N) ? W[(long)k * N + n] : 0.f;
    }
    __syncthreads();
#pragma unroll
    for (int i = 0; i < 4; i++) {
        int n = n0 + ty + i * 8, k = k0 + tx;
        if (n < Npad && k < K) WT[(long)n * K + k] = __float2bfloat16(t[tx][ty + i * 8]);
    }
}

// ---------------- f32 -> bf16 elementwise ----------------
__global__ void cvt_kernel(const float4* __restrict__ x, ushort4* __restrict__ y, long n4)
{
    long i = (long)blockIdx.x * 256 + threadIdx.x;
    if (i >= n4) return;
    float4 v = x[i];
    __hip_bfloat16 a = __float2bfloat16(v.x), b = __float2bfloat16(v.y);
    __hip_bfloat16 c = __float2bfloat16(v.z), d = __float2bfloat16(v.w);
    ushort4 o = { *(ushort*)&a, *(ushort*)&b, *(ushort*)&c, *(ushort*)&d };
    y[i] = o;
}

// ---------------- RMSNorm, wave-per-row ----------------
__global__ void rmsnorm_f32(const float* __restrict__ x, const float* __restrict__ w,
                            __hip_bfloat16* __restrict__ out, int D, int xs, int os, long nrows)
{
    const int wv = threadIdx.x >> 6, lane = threadIdx.x & 63;
    const long row = (long)blockIdx.x * 4 + wv;
    if (row >= nrows) return;
    const float* xr = x + row * xs;
    float ss = 0.f;
    for (int i = lane; i < D; i += 64) { float v = xr[i]; ss += v * v; }
    for (int o = 32; o; o >>= 1) ss += __shfl_xor(ss, o);
    const float sc = rsqrtf(ss / D + 1e-5f);
    __hip_bfloat16* orow = out + row * os;
    for (int i = lane; i < D; i += 64) orow[i] = __float2bfloat16(xr[i] * sc * w[i]);
}
__global__ void rmsnorm_b16(const __hip_bfloat16* __restrict__ x, const float* __restrict__ w,
                            __hip_bfloat16* __restrict__ out, int D, int xs, int os, long nrows)
{
    const int wv = threadIdx.x >> 6, lane = threadIdx.x & 63;
    const long row = (long)blockIdx.x * 4 + wv;
    if (row >= nrows) return;
    const __hip_bfloat16* xr = x + row * xs;
    float ss = 0.f;
    for (int i = lane; i < D; i += 64) { float v = bf2f(xr[i]); ss += v * v; }
    for (int o = 32; o; o >>= 1) ss += __shfl_xor(ss, o);
    const float sc = rsqrtf(ss / D + 1e-5f);
    __hip_bfloat16* orow = out + row * os;
    for (int i = lane; i < D; i += 64) orow[i] = __float2bfloat16(bf2f(xr[i]) * sc * w[i]);
}

// ---------------- fused attention ----------------
__global__ __launch_bounds__(256) void attn_kernel(
    const __hip_bfloat16* __restrict__ QKV, __hip_bfloat16* __restrict__ O)
{
    __shared__ float Qs[64 * 100];
    __shared__ float Ks[64 * 100];
    const int b = blockIdx.x >> 3, h = blockIdx.x & 7;
    const int tid = threadIdx.x;
    const long base = (long)b * 64 * 2304 + h * 96;
    for (int i = tid; i < 6144; i += 256) {
        int t = i / 96, d = i - t * 96;
        Qs[t * 100 + d] = bf2f(QKV[base + (long)t * 2304 + d]);
        int g = ((d >> 2) ^ ((t >> 4) & 3)) << 2;
        Ks[t * 100 + g + (d & 3)] = bf2f(QKV[base + (long)t * 2304 + 768 + d]);
    }
    __syncthreads();
    const int i_ = tid >> 2, j0 = (tid & 3) << 4;
    float sv[16];
#pragma unroll
    for (int jj = 0; jj < 16; jj++) sv[jj] = 0.f;
    for (int d0 = 0; d0 < 96; d0 += 4) {
        const float4 q4 = *(const float4*)&Qs[i_ * 100 + d0];
#pragma unroll
        for (int jj = 0; jj < 16; jj++) {
            const int r = j0 + jj;
            const int g = (((d0 >> 2) ^ ((r >> 4) & 3)) << 2);
            const float4 k4 = *(const float4*)&Ks[r * 100 + g];
            sv[jj] += q4.x * k4.x + q4.y * k4.y + q4.z * k4.z + q4.w * k4.w;
        }
    }
    const float scale = 0.102062072615966f;
    float mx = sv[0] * scale;
#pragma unroll
    for (int jj = 0; jj < 16; jj++) { sv[jj] *= scale; mx = fmaxf(mx, sv[jj]); }
    mx = fmaxf(mx, __shfl_xor(mx, 1));
    mx = fmaxf(mx, __shfl_xor(mx, 2));
    float sum = 0.f;
#pragma unroll
    for (int jj = 0; jj < 16; jj++) { sv[jj] = expf(sv[jj] - mx); sum += sv[jj]; }
    sum += __shfl_xor(sum, 1);
    sum += __shfl_xor(sum, 2);
    const float inv = 1.f / sum;
    __syncthreads();
    float* Ps = Qs;
#pragma unroll
    for (int jj = 0; jj < 16; jj++) Ps[i_ * 65 + j0 + jj] = sv[jj] * inv;
    float* Vs = Ks;
    for (int i = tid; i < 6144; i += 256) {
        int t = i / 96, d = i - t * 96;
        Vs[t * 100 + d] = bf2f(QKV[base + (long)t * 2304 + 1536 + d]);
    }
    __syncthreads();
    const int t_ = tid & 63, dg = (tid >> 6) * 24;
    float o4[24];
#pragma unroll
    for (int c = 0; c < 24; c++) o4[c] = 0.f;
    for (int k = 0; k < 64; k++) {
        const float p = Ps[t_ * 65 + k];
#pragma unroll
        for (int c = 0; c < 6; c++) {
            const float4 v4 = *(const float4*)&Vs[k * 100 + dg + c * 4];
            o4[c * 4 + 0] += p * v4.x; o4[c * 4 + 1] += p * v4.y;
            o4[c * 4 + 2] += p * v4.z; o4[c * 4 + 3] += p * v4.w;
        }
    }
    const long ob = (long)(b * 64 + t_) * 768 + h * 96 + dg;
#pragma unroll
    for (int c = 0; c < 24; c++) O[ob + c] = __float2bfloat16(o4[c]);
}

// ---------------- transpose p (B,N,T,D) -> z (B,T,N,D) ----------------
__global__ void transpose_kernel(const float* __restrict__ P, float* __restrict__ Z)
{
    long lin = (long)blockIdx.x * 256 + threadIdx.x;
    if (lin >= HALF) return;
    int d = (int)(lin % 768);
    long rowz = lin / 768;
    int n = rowz & 127, t = (int)((rowz >> 7) & 63), b = (int)(rowz >> 13);
    long rowp = ((long)(b * 128 + n)) * 64 + t;
    Z[lin] = P[rowp * 768 + d];
}

// -------- causal depthwise conv + SiLU: x-part -> bf16 xc, B/C -> bf16 bcB -----
__global__ void conv_kernel(const __hip_bfloat16* __restrict__ zx,
                            const float* __restrict__ cw, const float* __restrict__ cb,
                            __hip_bfloat16* __restrict__ xc, __hip_bfloat16* __restrict__ bcB,
                            long rows)
{
    long lin = (long)blockIdx.x * 256 + threadIdx.x;
    if (lin >= rows * 1664) return;
    int c = (int)(lin % 1664);
    long r = lin / 1664;
    int n = (int)(r & 127);
    float acc = cb[c];
#pragma unroll
    for (int k = 0; k < 4; k++) {
        int nn = n - 3 + k;
        if (nn >= 0) acc += cw[k * 1664 + c] * bf2f(zx[(r - 3 + k) * 3328 + 1536 + c]);
    }
    acc = acc / (1.f + expf(-acc));
    if (c < 1536) xc[r * 1664 + c] = __float2bfloat16(acc);
    else          bcB[r * 128 + (c - 1536)] = __float2bfloat16(acc);
}

// ---------------- dt = softplus(dt_raw + bias) -> f32 side buffer ----------------
__global__ void dt_kernel(const __hip_bfloat16* __restrict__ zx, const float* __restrict__ bias,
                          float* __restrict__ dtf, long count)
{
    long lin = (long)blockIdx.x * 256 + threadIdx.x;
    if (lin >= count) return;
    int h = (int)(lin % 24);
    long r = lin / 24;
    float v = bf2f(zx[r * 3328 + 3200 + h]) + bias[h];
    dtf[lin] = (v > 0.f) ? v + log1pf(expf(-v)) : log1pf(expf(v));
}

// ======== SSD (chunked-scan) kernel: block per (bt, h); MFMA everywhere ========
// G = C@B^T (128x128, K=64); M = tril(G * exp(cum_t - cum_j) * dt_j);
// Y = M@X (128x64, K=128); y = (Y + Dh*x) * silu(z) -> xc.
// If hout: h_T = (X*diag(w))^T @ B  (64x64, K=128), w_j = exp(cumT-cum_j)*dt_j.
__global__ __launch_bounds__(256) void ssd_kernel(
    const __hip_bfloat16* __restrict__ zx0, const float* __restrict__ dtf0,
    const __hip_bfloat16* __restrict__ bcB0, __hip_bfloat16* __restrict__ xc0,
    const float* __restrict__ Alog, const float* __restrict__ Dskip,
    float* __restrict__ hout, int bt0)
{
    __shared__ __align__(16) char SM[50688];
    __hip_bfloat16* Cl  = (__hip_bfloat16*)SM;            // [2][128][32]
    __hip_bfloat16* Bl  = Cl + 8192;                      // [2][128][32]
    __hip_bfloat16* Ml  = (__hip_bfloat16*)SM;            // [4][128][32] overlays Cl+Bl
    __hip_bfloat16* XTl = (__hip_bfloat16*)(SM + 32768);  // [4][64][32]  (X^T: [p][t])
    __hip_bfloat16* BTl = (__hip_bfloat16*)SM;            // [4][64][32]  overlays Ml (hT)
    float* cum = (float*)(SM + 49152);                    // [128]
    float* dtl = cum + 128;                               // [128]
    float* wl  = dtl + 128;                               // [128]

    const int tid = threadIdx.x;
    const int wid = tid >> 6, lane = tid & 63;
    const int lrow = lane & 15, lk = lane >> 4;
    const int btl = blockIdx.x / 24, h = blockIdx.x % 24;
    const long rowbase = (long)btl * 128;

    const __hip_bfloat16* zxp = zx0 + rowbase * 3328 + h * 64;
    const float* dtp = dtf0 + rowbase * 24;
    const __hip_bfloat16* bcp = bcB0 + rowbase * 128;
    __hip_bfloat16* xcp = xc0 + rowbase * 1664 + h * 64;

    const float A  = -expf(Alog[h]);
    const float Dh = Dskip[h];

    // ---- stage B (cols 0..63) and C (cols 64..127) with m97 XOR layout ----
#pragma unroll
    for (int i = 0; i < 4; i++) {
        const int v = tid + i * 256;          // 0..1023
        const int row = v >> 3, c8 = v & 7;
        const int kst = c8 >> 2, ch = c8 & 3;
        const int slot = ch ^ (row & 3);
        bf16x8 vB = *(const bf16x8*)(const void*)&bcp[(long)row * 128 + c8 * 8];
        bf16x8 vC = *(const bf16x8*)(const void*)&bcp[(long)row * 128 + 64 + c8 * 8];
        *(bf16x8*)(void*)&Bl[(kst * 128 + row) * 32 + slot * 8] = vB;
        *(bf16x8*)(void*)&Cl[(kst * 128 + row) * 32 + slot * 8] = vC;
    }
    // ---- stage X^T: [p][t] with XOR layout; wave wid covers t = wid*32..+31 ----
    for (int i = 0; i < 32; i++) {
        const int t = wid * 32 + i;
        const int slot = (i >> 3) ^ (lane & 3);
        XTl[(wid * 64 + lane) * 32 + slot * 8 + (i & 7)] = xcp[(long)t * 1664 + lane];
    }
    // ---- dt row ----
    if (tid < 128) dtl[tid] = dtp[(long)tid * 24 + h];
    __syncthreads();
    if (tid < 128) cum[tid] = dtl[tid] * A;
    __syncthreads();
    for (int off = 1; off < 128; off <<= 1) {
        float v = 0.f;
        if (tid < 128 && tid >= off) v = cum[tid - off];
        __syncthreads();
        if (tid < 128) cum[tid] += v;
        __syncthreads();
    }
    if (tid < 128) wl[tid] = expf(cum[127] - cum[tid]) * dtl[tid];
    __syncthreads();

    // ---- GEMM1: G[t][j] = sum_s C[t][s] B[j][s]  (each wave: 64x64 quarter) ----
    const int wr1 = (wid >> 1) * 64, wc1 = (wid & 1) * 64;
    const int ck = (lk ^ (lrow & 3)) * 8;
    f32x4 a1[4][4];
#pragma unroll
    for (int m = 0; m < 4; m++)
#pragma unroll
        for (int n = 0; n < 4; n++) a1[m][n] = f32x4{0.f, 0.f, 0.f, 0.f};
#pragma unroll
    for (int kst = 0; kst < 2; kst++) {
        bf16x8 ca[4], bb[4];
#pragma unroll
        for (int m = 0; m < 4; m++)
            ca[m] = *(const bf16x8*)(const void*)&Cl[(kst * 128 + wr1 + m * 16 + lrow) * 32 + ck];
#pragma unroll
        for (int n = 0; n < 4; n++)
            bb[n] = *(const bf16x8*)(const void*)&Bl[(kst * 128 + wc1 + n * 16 + lrow) * 32 + ck];
#pragma unroll
        for (int m = 0; m < 4; m++)
#pragma unroll
            for (int n = 0; n < 4; n++)
                a1[m][n] = __builtin_amdgcn_mfma_f32_16x16x32_bf16(ca[m], bb[n], a1[m][n], 0, 0, 0);
    }
    __syncthreads();   // done reading Cl/Bl; M overwrites them

    // ---- epilogue1: mask+scale -> M (bf16, XOR layout rows=t, k=j) ----
#pragma unroll
    for (int m = 0; m < 4; m++) {
        const int tb = wr1 + m * 16 + lk * 4;
        const f32x4 c4 = *(const f32x4*)&cum[tb];
#pragma unroll
        for (int n = 0; n < 4; n++) {
            const int j = wc1 + n * 16 + lrow;
            const float cj = cum[j], dj = dtl[j];
            const int jst = j >> 5, jc = (j >> 3) & 3, je = j & 7;
#pragma unroll
            for (int jj = 0; jj < 4; jj++) {
                const int t = tb + jj;
                float val = 0.f;
                if (j <= t) val = a1[m][n][jj] * expf(c4[jj] - cj) * dj;
                Ml[(jst * 128 + t) * 32 + ((jc ^ (t & 3)) * 8) + je] = __float2bfloat16(val);
            }
        }
    }
    __syncthreads();

    // ---- GEMM2: Y[t][p] = sum_j M[t][j] X[j][p]  (wave: 64(t) x 32(p)) ----
    const int wr2 = (wid >> 1) * 64, wc2 = (wid & 1) * 32;
    f32x4 a2[4][2];
#pragma unroll
    for (int m = 0; m < 4; m++)
#pragma unroll
        for (int n = 0; n < 2; n++) a2[m][n] = f32x4{0.f, 0.f, 0.f, 0.f};
#pragma unroll
    for (int kst = 0; kst < 4; kst++) {
        bf16x8 am[4], bn[2];
#pragma unroll
        for (int m = 0; m < 4; m++)
            am[m] = *(const bf16x8*)(const void*)&Ml[(kst * 128 + wr2 + m * 16 + lrow) * 32 + ck];
#pragma unroll
        for (int n = 0; n < 2; n++)
            bn[n] = *(const bf16x8*)(const void*)&XTl[(kst * 64 + wc2 + n * 16 + lrow) * 32 + ck];
#pragma unroll
        for (int m = 0; m < 4; m++)
#pragma unroll
            for (int n = 0; n < 2; n++)
                a2[m][n] = __builtin_amdgcn_mfma_f32_16x16x32_bf16(am[m], bn[n], a2[m][n], 0, 0, 0);
    }

    // ---- epilogue2: y = (Y + Dh*x) * silu(z) -> xc (global) ----
#pragma unroll
    for (int m = 0; m < 4; m++) {
        const int tb = wr2 + m * 16 + lk * 4;
#pragma unroll
        for (int n = 0; n < 2; n++) {
            const int p = wc2 + n * 16 + lrow;
#pragma unroll
            for (int jj = 0; jj < 4; jj++) {
                const int t = tb + jj;
                const float x = bf2f(XTl[((t >> 5) * 64 + p) * 32 + ((((t >> 3) & 3) ^ (p & 3)) * 8) + (t & 7)]);
                const float zg = bf2f(zxp[(long)t * 3328 + p]);
                const float y = (a2[m][n][jj] + Dh * x) * (zg / (1.f + expf(-zg)));
                xcp[(long)t * 1664 + p] = __float2bfloat16(y);
            }
        }
    }

    // ---- optional h_T = sum_j w_j x[j][p] B[j][s] ----
    if (hout) {
        __syncthreads();   // all Ml reads done; BT overlays it
        for (int i = 0; i < 32; i++) {
            const int j = wid * 32 + i;
            const int slot = (i >> 3) ^ (lane & 3);
            BTl[(wid * 64 + lane) * 32 + slot * 8 + (j & 7)] = bcp[(long)j * 128 + lane];
        }
        __syncthreads();
        const int wrp = (wid >> 1) * 32, wcs = (wid & 1) * 32;
        f32x4 a3[2][2];
#pragma unroll
        for (int m = 0; m < 2; m++)
#pragma unroll
            for (int n = 0; n < 2; n++) a3[m][n] = f32x4{0.f, 0.f, 0.f, 0.f};
#pragma unroll
        for (int kst = 0; kst < 4; kst++) {
            const int jb = kst * 32 + lk * 8;
            const f32x4 wa = *(const f32x4*)&wl[jb];
            const f32x4 wb = *(const f32x4*)&wl[jb + 4];
            bf16x8 xw[2], bn[2];
#pragma unroll
            for (int m = 0; m < 2; m++) {
                bf16x8 xr = *(const bf16x8*)(const void*)&XTl[(kst * 64 + wrp + m * 16 + lrow) * 32 + ck];
                bf16x8 t;
#pragma unroll
                for (int e = 0; e < 4; e++) t[e] = (__bf16)((float)xr[e] * wa[e]);
#pragma unroll
                for (int e = 0; e < 4; e++) t[4 + e] = (__bf16)((float)xr[4 + e] * wb[e]);
                xw[m] = t;
            }
#pragma unroll
            for (int n = 0; n < 2; n++)
                bn[n] = *(const bf16x8*)(const void*)&BTl[(kst * 64 + wcs + n * 16 + lrow) * 32 + ck];
#pragma unroll
            for (int m = 0; m < 2; m++)
#pragma unroll
                for (int n = 0; n < 2; n++)
                    a3[m][n] = __builtin_amdgcn_mfma_f32_16x16x32_bf16(xw[m], bn[n], a3[m][n], 0, 0, 0);
        }
        float* hp = hout + ((long)(bt0 + btl) * 24 + h) * 4096;
#pragma unroll
        for (int m = 0; m < 2; m++) {
            const int pb = wrp + m * 16 + lk * 4;
#pragma unroll
            for (int n = 0; n < 2; n++) {
                const int s = wcs + n * 16 + lrow;
#pragma unroll
                for (int jj = 0; jj < 4; jj++)
                    hp[(long)(pb + jj) * 64 + s] = a3[m][n][jj];
            }
        }
    }
}

// ---------------- host orchestration ----------------
extern "C" void kernel_launch(void* const* d_in, const int* in_sizes, int n_in,
                              void* d_out, int out_size, void* d_ws, size_t ws_size,
                              hipStream_t stream)
{
    const float* precepts  = (const float*)d_in[0];
    const float* actions   = (const float*)d_in[1];
    const float* attn_n1   = (const float*)d_in[2];
    const float* Wq        = (const float*)d_in[3];
    const float* Wk        = (const float*)d_in[4];
    const float* Wv        = (const float*)d_in[5];
    const float* Wo        = (const float*)d_in[6];
    const float* attn_n2   = (const float*)d_in[7];
    const float* ffn_w1    = (const float*)d_in[8];
    const float* ffn_b1    = (const float*)d_in[9];
    const float* ffn_w2    = (const float*)d_in[10];
    const float* ffn_b2    = (const float*)d_in[11];
    const float* ssm_norm  = (const float*)d_in[12];
    const float* in_proj   = (const float*)d_in[13];
    const float* conv_w    = (const float*)d_in[14];
    const float* conv_b    = (const float*)d_in[15];
    const float* dt_bias   = (const float*)d_in[16];
    const float* A_log     = (const float*)d_in[17];
    const float* D_skip    = (const float*)d_in[18];
    const float* mamba_nw  = (const float*)d_in[19];
    const float* out_proj  = (const float*)d_in[20];
    const float* proj_w    = (const float*)d_in[21];
    const float* proj_b    = (const float*)d_in[22];

    float* out  = (float*)d_out;
    float* Z    = out;            // z residual in out[0:HALF], dead before final GEMM
    float* P    = out + HALF;     // attention residual, dead before h_last written
    float* hout = out + HALF;

    // ---- ws: bf16 transposed weights, then phase-union scratch ----
    __hip_bfloat16* wb = (__hip_bfloat16*)d_ws;
    long wo = 0;
    auto walloc = [&](long els) { __hip_bfloat16* p = wb + wo; wo += els; return p; };
    __hip_bfloat16* WqkvT = walloc(4L * 2304 * 768);
    __hip_bfloat16* W1T   = walloc(4L * 3072 * 768);
    __hip_bfloat16* W2T   = walloc(4L * 768 * 3072);
    __hip_bfloat16* inT   = walloc(4L * 3328 * 768);
    __hip_bfloat16* outT  = walloc(4L * 768 * 1536);
    __hip_bfloat16* projT = walloc(768L * 768);
    __hip_bfloat16* WoT   = walloc(4L * 768 * 768);
    char* pbase = (char*)(wb + ((wo + 255) & ~255L));
    const size_t used_w = (size_t)(pbase - (char*)d_ws);
    const size_t avail = ws_size > used_w ? ws_size - used_w : 0;

    int CB = 512;                 // attention chunk
    while (CB > 8 && (unsigned long long)CB * 884736ull > avail) CB >>= 1;
    int CBT = 256;                // mamba chunk (per-row bytes = 14944, x128 rows)
    while (CBT > 2 && (unsigned long long)CBT * 1912832ull > avail) CBT >>= 1;

    auto gemm = [&](const __hip_bfloat16* A, const __hip_bfloat16* BT, const float* bias,
                    void* C, int ldc, int M, int N, int Npad, int K, int flags, int moff) {
        dim3 g(Npad / 128, M / 128);
        hipLaunchKernelGGL(gemm_bf16, g, dim3(256), 0, stream,
                           A, BT, bias, C, ldc, M, N, K, flags, moff);
    };
    auto cvtT = [&](const float* W, __hip_bfloat16* WT, int K, int N, int Npad) {
        dim3 g((Npad + 31) / 32, (K + 31) / 32);
        hipLaunchKernelGGL(convT_kernel, g, dim3(256), 0, stream, W, WT, K, N, Npad);
    };
    auto cvt = [&](const float* x, __hip_bfloat16* y, long n) {
        long n4 = n / 4;
        hipLaunchKernelGGL(cvt_kernel, dim3((n4 + 255) / 256), dim3(256), 0, stream,
                           (const float4*)x, (ushort4*)y, n4);
    };
    auto rmsF = [&](const float* x, const float* w, __hip_bfloat16* o, int D, int xs, int os, long rows) {
        hipLaunchKernelGGL(rmsnorm_f32, dim3((rows + 3) / 4), dim3(256), 0, stream,
                           x, w, o, D, xs, os, rows);
    };
    auto rmsB = [&](const __hip_bfloat16* x, const float* w, __hip_bfloat16* o, int D, int xs, int os, long rows) {
        hipLaunchKernelGGL(rmsnorm_b16, dim3((rows + 3) / 4), dim3(256), 0, stream,
                           x, w, o, D, xs, os, rows);
    };

    // ---- weight conversion ----
    for (int l = 0; l < 4; l++) {
        cvtT(Wq + (long)l * 589824, WqkvT + (long)l * 2304 * 768,                768, 768, 768);
        cvtT(Wk + (long)l * 589824, WqkvT + (long)l * 2304 * 768 +  768L * 768,  768, 768, 768);
        cvtT(Wv + (long)l * 589824, WqkvT + (long)l * 2304 * 768 + 1536L * 768,  768, 768, 768);
        cvtT(Wo + (long)l * 589824, WoT + (long)l * 589824, 768, 768, 768);
        cvtT(ffn_w1 + (long)l * 2359296, W1T + (long)l * 2359296, 768, 3072, 3072);
        cvtT(ffn_w2 + (long)l * 2359296, W2T + (long)l * 2359296, 3072, 768, 768);
    }
    for (int m = 0; m < 4; m++) {
        cvtT(in_proj + (long)m * 768 * 3224, inT + (long)m * 3328 * 768, 768, 3224, 3328);
        cvtT(out_proj + (long)m * 1536 * 768, outT + (long)m * 768 * 1536, 1536, 768, 768);
    }
    cvtT(proj_w, projT, 768, 768, 768);

    // ---- attention stack ----
    hipMemcpyAsync(P, precepts, HALF * sizeof(float), hipMemcpyDeviceToDevice, stream);
    {
        const long rA = (long)CB * 64;
        __hip_bfloat16* bufA   = (__hip_bfloat16*)pbase;        // rA x 768
        __hip_bfloat16* actB   = bufA + rA * 768;               // rA x 768
        __hip_bfloat16* bufQKV = actB + rA * 768;               // rA x 2304
        __hip_bfloat16* bufH   = bufQKV + rA * 2304;            // rA x 3072
        const int nac = 512 / CB;
        const int Mr = (int)rA;
        if (nac == 1) cvt(actions, actB, rA * 768);
        for (int layer = 0; layer < 4; layer++) {
            const bool cross = ((layer + 1) % 2) == 0;
            for (int c = 0; c < nac; c++) {
                const long tok0 = (long)c * rA;
                float* Pc = P + tok0 * 768;
                rmsF(Pc, attn_n1 + layer * 768, bufA, 768, 768, 768, Mr);
                if (!cross) {
                    gemm(bufA, WqkvT + (long)layer * 2304 * 768, nullptr, bufQKV, 2304,
                         Mr, 2304, 2304, 768, FLAG_BF16, 0);
                } else {
                    if (nac != 1) cvt(actions + tok0 * 768, actB, rA * 768);
                    gemm(bufA, WqkvT + (long)layer * 2304 * 768, nullptr, bufQKV, 2304,
                         Mr, 768, 768, 768, FLAG_BF16, 0);
                    gemm(actB, WqkvT + (long)layer * 2304 * 768 + 768L * 768, nullptr,
                         bufQKV + 768, 2304, Mr, 1536, 1536, 768, FLAG_BF16, 0);
                }
                hipLaunchKernelGGL(attn_kernel, dim3(CB * 8), dim3(256), 0, stream,
                                   bufQKV, bufA);
                gemm(bufA, WoT + (long)layer * 589824, nullptr, Pc, 768,
                     Mr, 768, 768, 768, FLAG_ACC, 0);
                rmsF(Pc, attn_n2 + layer * 768, bufA, 768, 768, 768, Mr);
                gemm(bufA, W1T + (long)layer * 2359296, ffn_b1 + layer * 3072, bufH, 3072,
                     Mr, 3072, 3072, 768, FLAG_GELU | FLAG_BF16, 0);
                gemm(bufH, W2T + (long)layer * 2359296, ffn_b2 + layer * 768, Pc, 768,
                     Mr, 768, 768, 3072, FLAG_ACC, 0);
            }
        }
    }

    // ---- transpose to SSM layout ----
    hipLaunchKernelGGL(transpose_kernel, dim3((int)((HALF + 255) / 256)), dim3(256), 0, stream, P, Z);

    // ---- mamba blocks ----
    {
        const long rM = (long)CBT * 128;
        __hip_bfloat16* xn  = (__hip_bfloat16*)pbase;            // rM x 768
        __hip_bfloat16* zx  = xn + rM * 768;                     // rM x 3328
        float*          dtf = (float*)(zx + rM * 3328);          // rM x 24
        __hip_bfloat16* xc  = (__hip_bfloat16*)(dtf + rM * 24);  // rM x 1664
        __hip_bfloat16* yb  = xc + rM * 1664;                    // rM x 1536
        __hip_bfloat16* bcB = yb + rM * 1536;                    // rM x 128
        const int nmc = 256 / CBT;
        const int Mr = (int)rM;
        for (int m = 0; m < 4; m++) {
            for (int c = 0; c < nmc; c++) {
                float* Zc = Z + (long)c * rM * 768;
                rmsF(Zc, ssm_norm + m * 768, xn, 768, 768, 768, Mr);
                gemm(xn, inT + (long)m * 3328 * 768, nullptr, zx, 3328,
                     Mr, 3224, 3328, 768, FLAG_BF16, 0);
                const long convn = rM * 1664;
                hipLaunchKernelGGL(conv_kernel, dim3((int)((convn + 255) / 256)), dim3(256), 0, stream,
                                   zx, conv_w + m * 4 * 1664, conv_b + m * 1664, xc, bcB, rM);
                const long dtn = rM * 24;
                hipLaunchKernelGGL(dt_kernel, dim3((int)((dtn + 255) / 256)), dim3(256), 0, stream,
                                   zx, dt_bias + m * 24, dtf, dtn);
                hipLaunchKernelGGL(ssd_kernel, dim3(CBT * 24), dim3(256), 0, stream,
                                   zx, dtf, bcB, xc, A_log + m * 24, D_skip + m * 24,
                                   (m == 3) ? hout : nullptr, c * CBT);
                rmsB(xc, mamba_nw + m * 1536, yb, 1536, 1664, 1536, Mr);
                gemm(yb, outT + (long)m * 768 * 1536, nullptr, Zc, 768,
                     Mr, 768, 768, 1536, FLAG_ACC, 0);
            }
        }
    }

    // ---- final projection ----
    {
        __hip_bfloat16* Zb = (__hip_bfloat16*)pbase;
        cvt(Z, Zb, HALF);
        gemm(Zb, projT, proj_b, out, 768, 32768, 768, 768, 768, FLAG_PERM, 0);
    }
}

// Round 7
// 8018.934 us; speedup vs baseline: 1.3026x; 1.1357x over previous
//
#include <hip/hip_runtime.h>
#include <hip/hip_bf16.h>
#include <math.h>

// ---------------- model dims ----------------
constexpr long TOK  = 32768;            // B*N*T
constexpr long HALF = TOK * 768;
constexpr int FLAG_ACC = 1, FLAG_GELU = 2, FLAG_PERM = 4, FLAG_BF16 = 8;

typedef __bf16 bf16x8 __attribute__((ext_vector_type(8)));
typedef float  f32x4  __attribute__((ext_vector_type(4)));

__device__ __forceinline__ void gload_lds16(const void* g, void* l) {
    __builtin_amdgcn_global_load_lds(
        (const __attribute__((address_space(1))) void*)g,
        (__attribute__((address_space(3))) void*)l, 16, 0, 0);
}
__device__ __forceinline__ float bf2f(__hip_bfloat16 v) { return __bfloat162float(v); }

// ---------------- bf16 MFMA GEMM: 128x128 tile, 2-phase dbuf, vector epilogue ----
__global__ __launch_bounds__(256) void gemm_bf16(
    const __hip_bfloat16* __restrict__ A,
    const __hip_bfloat16* __restrict__ BT,
    const float* __restrict__ bias,
    void* __restrict__ Cv, int ldc,
    int M, int N, int K, int flags, int moff)
{
    __shared__ __hip_bfloat16 As[2][128 * 32];
    __shared__ __hip_bfloat16 Bs[2][128 * 32];
    const int tid = threadIdx.x;
    const int wv = tid >> 6, lane = tid & 63;
    // bijective XCD swizzle (m204)
    const int nwg = gridDim.x * gridDim.y;
    const int orig = blockIdx.y * gridDim.x + blockIdx.x;
    const int q8 = nwg >> 3, r8 = nwg & 7;
    const int xcd = orig & 7, off = orig >> 3;
    const int wgid = (xcd < r8 ? xcd * (q8 + 1) : r8 * (q8 + 1) + (xcd - r8) * q8) + off;
    const int bm = (wgid / gridDim.x) * 128, bn = (wgid % gridDim.x) * 128;
    const int wr = (wv >> 1) * 64, wc = (wv & 1) * 64;
    const int lrow = lane & 15, lk = lane >> 4;
    const int ck = (lk ^ (lrow & 3) ^ ((lrow >> 2) & 3)) * 8;   // 2-way-max bank key

    f32x4 acc[4][4];   // [n][m]: swapped-operand layout (lane: row=lrow, 4 consecutive cols)
#pragma unroll
    for (int n = 0; n < 4; n++)
#pragma unroll
        for (int m = 0; m < 4; m++) acc[n][m] = f32x4{0.f, 0.f, 0.f, 0.f};

    const int nk = K >> 5;
    auto stage = [&](int kt, int buf) {
#pragma unroll
        for (int i = 0; i < 2; i++) {
            const int lin = i * 256 + tid;
            const int row = lin >> 2;
            const int ks  = (((lin & 3) ^ (row & 3) ^ ((row >> 2) & 3)) * 8);
            const long asrc = (long)(bm + row) * K + kt * 32 + ks;
            const long bsrc = (long)(bn + row) * K + kt * 32 + ks;
            char* la = (char*)&As[buf][0] + (i * 256 + wv * 64) * 16;
            char* lb = (char*)&Bs[buf][0] + (i * 256 + wv * 64) * 16;
            gload_lds16(A + asrc, la);
            gload_lds16(BT + bsrc, lb);
        }
    };

    stage(0, 0);
    __syncthreads();
    for (int kt = 0; kt < nk; kt++) {
        const int cur = kt & 1;
        if (kt + 1 < nk) stage(kt + 1, cur ^ 1);   // overlap next-tile loads with compute
        bf16x8 af[4], bfr[4];
#pragma unroll
        for (int m = 0; m < 4; m++) {
            af[m]  = *(const bf16x8*)(const void*)&As[cur][(wr + m * 16 + lrow) * 32 + ck];
            bfr[m] = *(const bf16x8*)(const void*)&Bs[cur][(wc + m * 16 + lrow) * 32 + ck];
        }
#pragma unroll
        for (int n = 0; n < 4; n++)
#pragma unroll
            for (int m = 0; m < 4; m++)
                acc[n][m] = __builtin_amdgcn_mfma_f32_16x16x32_bf16(bfr[n], af[m], acc[n][m], 0, 0, 0);
        __syncthreads();   // drains vmcnt: next buffer ready; reads of cur done
    }

    float* Cf = (float*)Cv;
    __hip_bfloat16* Cb = (__hip_bfloat16*)Cv;
#pragma unroll
    for (int n = 0; n < 4; n++) {
        const int gcb = bn + wc + n * 16 + lk * 4;    // 4 consecutive columns
        f32x4 b4 = f32x4{0.f, 0.f, 0.f, 0.f};
        if (bias) b4 = *(const f32x4*)&bias[gcb];
#pragma unroll
        for (int m = 0; m < 4; m++) {
            const int gr = bm + wr + m * 16 + lrow;
            f32x4 v = acc[n][m] + b4;
            if (flags & FLAG_GELU) {
#pragma unroll
                for (int j = 0; j < 4; j++) {
                    const float x = v[j];
                    const float u = 1.5957691216057308f * (x + 0.044715f * x * x * x);
                    v[j] = x / (1.f + __expf(-u));   // == 0.5x(1+tanh(u/2))
                }
            }
            if (flags & FLAG_PERM) {
                const int mg = moff + gr;
                const int b_ = mg >> 13, t_ = (mg >> 7) & 63, n_ = mg & 127;
                *(f32x4*)&Cf[(((long)(b_ * 128 + n_)) * 64 + t_) * ldc + gcb] = v;
            } else if (flags & FLAG_BF16) {
                __hip_bfloat16 o0 = __float2bfloat16(v[0]), o1 = __float2bfloat16(v[1]);
                __hip_bfloat16 o2 = __float2bfloat16(v[2]), o3 = __float2bfloat16(v[3]);
                ushort4 o = { *(ushort*)&o0, *(ushort*)&o1, *(ushort*)&o2, *(ushort*)&o3 };
                *(ushort4*)&Cb[(long)gr * ldc + gcb] = o;
            } else if (flags & FLAG_ACC) {
                float* dst = &Cf[(long)gr * ldc + gcb];
                f32x4 old = *(const f32x4*)dst;
                *(f32x4*)dst = old + v;
            } else {
                *(f32x4*)&Cf[(long)gr * ldc + gcb] = v;
            }
        }
    }
}

// ---------------- weight transpose-convert: W (KxN f32) -> WT (Npad x K bf16) ----
__global__ void convT_kernel(const float* __restrict__ W, __hip_bfloat16* __restrict__ WT,
                             int K, int N, int Npad)
{
    __shared__ float t[32][33];
    const int k0 = blockIdx.y * 32, n0 = blockIdx.x * 32;
    const int tx = threadIdx.x & 31, ty = threadIdx.x >> 5;
#pragma unroll
    for (int i = 0; i < 4; i++) {
        int k = k0 + ty + i * 8, n = n0 + tx;
        t[ty + i * 8][tx] = (k < K && n < N) ? W[(long)k * N + n] : 0.f;
    }
    __syncthreads();
#pragma unroll
    for (int i = 0; i < 4; i++) {
        int n = n0 + ty + i * 8, k = k0 + tx;
        if (n < Npad && k < K) WT[(long)n * K + k] = __float2bfloat16(t[tx][ty + i * 8]);
    }
}

// ---------------- f32 -> bf16 elementwise ----------------
__global__ void cvt_kernel(const float4* __restrict__ x, ushort4* __restrict__ y, long n4)
{
    long i = (long)blockIdx.x * 256 + threadIdx.x;
    if (i >= n4) return;
    float4 v = x[i];
    __hip_bfloat16 a = __float2bfloat16(v.x), b = __float2bfloat16(v.y);
    __hip_bfloat16 c = __float2bfloat16(v.z), d = __float2bfloat16(v.w);
    ushort4 o = { *(ushort*)&a, *(ushort*)&b, *(ushort*)&c, *(ushort*)&d };
    y[i] = o;
}

// ---------------- RMSNorm, wave-per-row ----------------
__global__ void rmsnorm_f32(const float* __restrict__ x, const float* __restrict__ w,
                            __hip_bfloat16* __restrict__ out, int D, int xs, int os, long nrows)
{
    const int wv = threadIdx.x >> 6, lane = threadIdx.x & 63;
    const long row = (long)blockIdx.x * 4 + wv;
    if (row >= nrows) return;
    const float* xr = x + row * xs;
    float ss = 0.f;
    for (int i = lane; i < D; i += 64) { float v = xr[i]; ss += v * v; }
    for (int o = 32; o; o >>= 1) ss += __shfl_xor(ss, o);
    const float sc = rsqrtf(ss / D + 1e-5f);
    __hip_bfloat16* orow = out + row * os;
    for (int i = lane; i < D; i += 64) orow[i] = __float2bfloat16(xr[i] * sc * w[i]);
}
__global__ void rmsnorm_b16(const __hip_bfloat16* __restrict__ x, const float* __restrict__ w,
                            __hip_bfloat16* __restrict__ out, int D, int xs, int os, long nrows)
{
    const int wv = threadIdx.x >> 6, lane = threadIdx.x & 63;
    const long row = (long)blockIdx.x * 4 + wv;
    if (row >= nrows) return;
    const __hip_bfloat16* xr = x + row * xs;
    float ss = 0.f;
    for (int i = lane; i < D; i += 64) { float v = bf2f(xr[i]); ss += v * v; }
    for (int o = 32; o; o >>= 1) ss += __shfl_xor(ss, o);
    const float sc = rsqrtf(ss / D + 1e-5f);
    __hip_bfloat16* orow = out + row * os;
    for (int i = lane; i < D; i += 64) orow[i] = __float2bfloat16(bf2f(xr[i]) * sc * w[i]);
}

// ---------------- fused attention ----------------
__global__ __launch_bounds__(256) void attn_kernel(
    const __hip_bfloat16* __restrict__ QKV, __hip_bfloat16* __restrict__ O)
{
    __shared__ float Qs[64 * 100];
    __shared__ float Ks[64 * 100];
    const int b = blockIdx.x >> 3, h = blockIdx.x & 7;
    const int tid = threadIdx.x;
    const long base = (long)b * 64 * 2304 + h * 96;
    for (int i = tid; i < 6144; i += 256) {
        int t = i / 96, d = i - t * 96;
        Qs[t * 100 + d] = bf2f(QKV[base + (long)t * 2304 + d]);
        int g = ((d >> 2) ^ ((t >> 4) & 3)) << 2;
        Ks[t * 100 + g + (d & 3)] = bf2f(QKV[base + (long)t * 2304 + 768 + d]);
    }
    __syncthreads();
    const int i_ = tid >> 2, j0 = (tid & 3) << 4;
    float sv[16];
#pragma unroll
    for (int jj = 0; jj < 16; jj++) sv[jj] = 0.f;
    for (int d0 = 0; d0 < 96; d0 += 4) {
        const float4 q4 = *(const float4*)&Qs[i_ * 100 + d0];
#pragma unroll
        for (int jj = 0; jj < 16; jj++) {
            const int r = j0 + jj;
            const int g = (((d0 >> 2) ^ ((r >> 4) & 3)) << 2);
            const float4 k4 = *(const float4*)&Ks[r * 100 + g];
            sv[jj] += q4.x * k4.x + q4.y * k4.y + q4.z * k4.z + q4.w * k4.w;
        }
    }
    const float scale = 0.102062072615966f;
    float mx = sv[0] * scale;
#pragma unroll
    for (int jj = 0; jj < 16; jj++) { sv[jj] *= scale; mx = fmaxf(mx, sv[jj]); }
    mx = fmaxf(mx, __shfl_xor(mx, 1));
    mx = fmaxf(mx, __shfl_xor(mx, 2));
    float sum = 0.f;
#pragma unroll
    for (int jj = 0; jj < 16; jj++) { sv[jj] = expf(sv[jj] - mx); sum += sv[jj]; }
    sum += __shfl_xor(sum, 1);
    sum += __shfl_xor(sum, 2);
    const float inv = 1.f / sum;
    __syncthreads();
    float* Ps = Qs;
#pragma unroll
    for (int jj = 0; jj < 16; jj++) Ps[i_ * 65 + j0 + jj] = sv[jj] * inv;
    float* Vs = Ks;
    for (int i = tid; i < 6144; i += 256) {
        int t = i / 96, d = i - t * 96;
        Vs[t * 100 + d] = bf2f(QKV[base + (long)t * 2304 + 1536 + d]);
    }
    __syncthreads();
    const int t_ = tid & 63, dg = (tid >> 6) * 24;
    float o4[24];
#pragma unroll
    for (int c = 0; c < 24; c++) o4[c] = 0.f;
    for (int k = 0; k < 64; k++) {
        const float p = Ps[t_ * 65 + k];
#pragma unroll
        for (int c = 0; c < 6; c++) {
            const float4 v4 = *(const float4*)&Vs[k * 100 + dg + c * 4];
            o4[c * 4 + 0] += p * v4.x; o4[c * 4 + 1] += p * v4.y;
            o4[c * 4 + 2] += p * v4.z; o4[c * 4 + 3] += p * v4.w;
        }
    }
    const long ob = (long)(b * 64 + t_) * 768 + h * 96 + dg;
#pragma unroll
    for (int c = 0; c < 24; c++) O[ob + c] = __float2bfloat16(o4[c]);
}

// ---------------- transpose p (B,N,T,D) -> z (B,T,N,D) ----------------
__global__ void transpose_kernel(const float* __restrict__ P, float* __restrict__ Z)
{
    long lin = (long)blockIdx.x * 256 + threadIdx.x;
    if (lin >= HALF) return;
    int d = (int)(lin % 768);
    long rowz = lin / 768;
    int n = rowz & 127, t = (int)((rowz >> 7) & 63), b = (int)(rowz >> 13);
    long rowp = ((long)(b * 128 + n)) * 64 + t;
    Z[lin] = P[rowp * 768 + d];
}

// -------- causal depthwise conv + SiLU: x-part -> bf16 xc, B/C -> bf16 bcB -----
__global__ void conv_kernel(const __hip_bfloat16* __restrict__ zx,
                            const float* __restrict__ cw, const float* __restrict__ cb,
                            __hip_bfloat16* __restrict__ xc, __hip_bfloat16* __restrict__ bcB,
                            long rows)
{
    long lin = (long)blockIdx.x * 256 + threadIdx.x;
    if (lin >= rows * 1664) return;
    int c = (int)(lin % 1664);
    long r = lin / 1664;
    int n = (int)(r & 127);
    float acc = cb[c];
#pragma unroll
    for (int k = 0; k < 4; k++) {
        int nn = n - 3 + k;
        if (nn >= 0) acc += cw[k * 1664 + c] * bf2f(zx[(r - 3 + k) * 3328 + 1536 + c]);
    }
    acc = acc / (1.f + expf(-acc));
    if (c < 1536) xc[r * 1664 + c] = __float2bfloat16(acc);
    else          bcB[r * 128 + (c - 1536)] = __float2bfloat16(acc);
}

// ---------------- dt = softplus(dt_raw + bias) -> f32 side buffer ----------------
__global__ void dt_kernel(const __hip_bfloat16* __restrict__ zx, const float* __restrict__ bias,
                          float* __restrict__ dtf, long count)
{
    long lin = (long)blockIdx.x * 256 + threadIdx.x;
    if (lin >= count) return;
    int h = (int)(lin % 24);
    long r = lin / 24;
    float v = bf2f(zx[r * 3328 + 3200 + h]) + bias[h];
    dtf[lin] = (v > 0.f) ? v + log1pf(expf(-v)) : log1pf(expf(v));
}

// ======== SSD (chunked-scan) kernel: block per (bt, h); MFMA everywhere ========
__global__ __launch_bounds__(256) void ssd_kernel(
    const __hip_bfloat16* __restrict__ zx0, const float* __restrict__ dtf0,
    const __hip_bfloat16* __restrict__ bcB0, __hip_bfloat16* __restrict__ xc0,
    const float* __restrict__ Alog, const float* __restrict__ Dskip,
    float* __restrict__ hout, int bt0)
{
    __shared__ __align__(16) char SM[50688];
    __hip_bfloat16* Cl  = (__hip_bfloat16*)SM;            // [2][128][32]
    __hip_bfloat16* Bl  = Cl + 8192;                      // [2][128][32]
    __hip_bfloat16* Ml  = (__hip_bfloat16*)SM;            // [4][128][32] overlays Cl+Bl
    __hip_bfloat16* XTl = (__hip_bfloat16*)(SM + 32768);  // [4][64][32]  (X^T: [p][t])
    __hip_bfloat16* BTl = (__hip_bfloat16*)SM;            // [4][64][32]  overlays Ml (hT)
    float* cum = (float*)(SM + 49152);                    // [128]
    float* dtl = cum + 128;                               // [128]
    float* wl  = dtl + 128;                               // [128]

    const int tid = threadIdx.x;
    const int wid = tid >> 6, lane = tid & 63;
    const int lrow = lane & 15, lk = lane >> 4;
    const int btl = blockIdx.x / 24, h = blockIdx.x % 24;
    const long rowbase = (long)btl * 128;

    const __hip_bfloat16* zxp = zx0 + rowbase * 3328 + h * 64;
    const float* dtp = dtf0 + rowbase * 24;
    const __hip_bfloat16* bcp = bcB0 + rowbase * 128;
    __hip_bfloat16* xcp = xc0 + rowbase * 1664 + h * 64;

    const float A  = -expf(Alog[h]);
    const float Dh = Dskip[h];

#pragma unroll
    for (int i = 0; i < 4; i++) {
        const int v = tid + i * 256;
        const int row = v >> 3, c8 = v & 7;
        const int kst = c8 >> 2, ch = c8 & 3;
        const int slot = ch ^ (row & 3);
        bf16x8 vB = *(const bf16x8*)(const void*)&bcp[(long)row * 128 + c8 * 8];
        bf16x8 vC = *(const bf16x8*)(const void*)&bcp[(long)row * 128 + 64 + c8 * 8];
        *(bf16x8*)(void*)&Bl[(kst * 128 + row) * 32 + slot * 8] = vB;
        *(bf16x8*)(void*)&Cl[(kst * 128 + row) * 32 + slot * 8] = vC;
    }
    for (int i = 0; i < 32; i++) {
        const int t = wid * 32 + i;
        const int slot = (i >> 3) ^ (lane & 3);
        XTl[(wid * 64 + lane) * 32 + slot * 8 + (i & 7)] = xcp[(long)t * 1664 + lane];
    }
    if (tid < 128) dtl[tid] = dtp[(long)tid * 24 + h];
    __syncthreads();
    if (tid < 128) cum[tid] = dtl[tid] * A;
    __syncthreads();
    for (int off = 1; off < 128; off <<= 1) {
        float v = 0.f;
        if (tid < 128 && tid >= off) v = cum[tid - off];
        __syncthreads();
        if (tid < 128) cum[tid] += v;
        __syncthreads();
    }
    if (tid < 128) wl[tid] = expf(cum[127] - cum[tid]) * dtl[tid];
    __syncthreads();

    const int wr1 = (wid >> 1) * 64, wc1 = (wid & 1) * 64;
    const int ck = (lk ^ (lrow & 3)) * 8;
    f32x4 a1[4][4];
#pragma unroll
    for (int m = 0; m < 4; m++)
#pragma unroll
        for (int n = 0; n < 4; n++) a1[m][n] = f32x4{0.f, 0.f, 0.f, 0.f};
#pragma unroll
    for (int kst = 0; kst < 2; kst++) {
        bf16x8 ca[4], bb[4];
#pragma unroll
        for (int m = 0; m < 4; m++)
            ca[m] = *(const bf16x8*)(const void*)&Cl[(kst * 128 + wr1 + m * 16 + lrow) * 32 + ck];
#pragma unroll
        for (int n = 0; n < 4; n++)
            bb[n] = *(const bf16x8*)(const void*)&Bl[(kst * 128 + wc1 + n * 16 + lrow) * 32 + ck];
#pragma unroll
        for (int m = 0; m < 4; m++)
#pragma unroll
            for (int n = 0; n < 4; n++)
                a1[m][n] = __builtin_amdgcn_mfma_f32_16x16x32_bf16(ca[m], bb[n], a1[m][n], 0, 0, 0);
    }
    __syncthreads();

#pragma unroll
    for (int m = 0; m < 4; m++) {
        const int tb = wr1 + m * 16 + lk * 4;
        const f32x4 c4 = *(const f32x4*)&cum[tb];
#pragma unroll
        for (int n = 0; n < 4; n++) {
            const int j = wc1 + n * 16 + lrow;
            const float cj = cum[j], dj = dtl[j];
            const int jst = j >> 5, jc = (j >> 3) & 3, je = j & 7;
#pragma unroll
            for (int jj = 0; jj < 4; jj++) {
                const int t = tb + jj;
                float val = 0.f;
                if (j <= t) val = a1[m][n][jj] * expf(c4[jj] - cj) * dj;
                Ml[(jst * 128 + t) * 32 + ((jc ^ (t & 3)) * 8) + je] = __float2bfloat16(val);
            }
        }
    }
    __syncthreads();

    const int wr2 = (wid >> 1) * 64, wc2 = (wid & 1) * 32;
    f32x4 a2[4][2];
#pragma unroll
    for (int m = 0; m < 4; m++)
#pragma unroll
        for (int n = 0; n < 2; n++) a2[m][n] = f32x4{0.f, 0.f, 0.f, 0.f};
#pragma unroll
    for (int kst = 0; kst < 4; kst++) {
        bf16x8 am[4], bn[2];
#pragma unroll
        for (int m = 0; m < 4; m++)
            am[m] = *(const bf16x8*)(const void*)&Ml[(kst * 128 + wr2 + m * 16 + lrow) * 32 + ck];
#pragma unroll
        for (int n = 0; n < 2; n++)
            bn[n] = *(const bf16x8*)(const void*)&XTl[(kst * 64 + wc2 + n * 16 + lrow) * 32 + ck];
#pragma unroll
        for (int m = 0; m < 4; m++)
#pragma unroll
            for (int n = 0; n < 2; n++)
                a2[m][n] = __builtin_amdgcn_mfma_f32_16x16x32_bf16(am[m], bn[n], a2[m][n], 0, 0, 0);
    }

#pragma unroll
    for (int m = 0; m < 4; m++) {
        const int tb = wr2 + m * 16 + lk * 4;
#pragma unroll
        for (int n = 0; n < 2; n++) {
            const int p = wc2 + n * 16 + lrow;
#pragma unroll
            for (int jj = 0; jj < 4; jj++) {
                const int t = tb + jj;
                const float x = bf2f(XTl[((t >> 5) * 64 + p) * 32 + ((((t >> 3) & 3) ^ (p & 3)) * 8) + (t & 7)]);
                const float zg = bf2f(zxp[(long)t * 3328 + p]);
                const float y = (a2[m][n][jj] + Dh * x) * (zg / (1.f + expf(-zg)));
                xcp[(long)t * 1664 + p] = __float2bfloat16(y);
            }
        }
    }

    if (hout) {
        __syncthreads();
        for (int i = 0; i < 32; i++) {
            const int j = wid * 32 + i;
            const int slot = (i >> 3) ^ (lane & 3);
            BTl[(wid * 64 + lane) * 32 + slot * 8 + (j & 7)] = bcp[(long)j * 128 + lane];
        }
        __syncthreads();
        const int wrp = (wid >> 1) * 32, wcs = (wid & 1) * 32;
        f32x4 a3[2][2];
#pragma unroll
        for (int m = 0; m < 2; m++)
#pragma unroll
            for (int n = 0; n < 2; n++) a3[m][n] = f32x4{0.f, 0.f, 0.f, 0.f};
#pragma unroll
        for (int kst = 0; kst < 4; kst++) {
            const int jb = kst * 32 + lk * 8;
            const f32x4 wa = *(const f32x4*)&wl[jb];
            const f32x4 wb = *(const f32x4*)&wl[jb + 4];
            bf16x8 xw[2], bn[2];
#pragma unroll
            for (int m = 0; m < 2; m++) {
                bf16x8 xr = *(const bf16x8*)(const void*)&XTl[(kst * 64 + wrp + m * 16 + lrow) * 32 + ck];
                bf16x8 t;
#pragma unroll
                for (int e = 0; e < 4; e++) t[e] = (__bf16)((float)xr[e] * wa[e]);
#pragma unroll
                for (int e = 0; e < 4; e++) t[4 + e] = (__bf16)((float)xr[4 + e] * wb[e]);
                xw[m] = t;
            }
#pragma unroll
            for (int n = 0; n < 2; n++)
                bn[n] = *(const bf16x8*)(const void*)&BTl[(kst * 64 + wcs + n * 16 + lrow) * 32 + ck];
#pragma unroll
            for (int m = 0; m < 2; m++)
#pragma unroll
                for (int n = 0; n < 2; n++)
                    a3[m][n] = __builtin_amdgcn_mfma_f32_16x16x32_bf16(xw[m], bn[n], a3[m][n], 0, 0, 0);
        }
        float* hp = hout + ((long)(bt0 + btl) * 24 + h) * 4096;
#pragma unroll
        for (int m = 0; m < 2; m++) {
            const int pb = wrp + m * 16 + lk * 4;
#pragma unroll
            for (int n = 0; n < 2; n++) {
                const int s = wcs + n * 16 + lrow;
#pragma unroll
                for (int jj = 0; jj < 4; jj++)
                    hp[(long)(pb + jj) * 64 + s] = a3[m][n][jj];
            }
        }
    }
}

// ---------------- host orchestration ----------------
extern "C" void kernel_launch(void* const* d_in, const int* in_sizes, int n_in,
                              void* d_out, int out_size, void* d_ws, size_t ws_size,
                              hipStream_t stream)
{
    const float* precepts  = (const float*)d_in[0];
    const float* actions   = (const float*)d_in[1];
    const float* attn_n1   = (const float*)d_in[2];
    const float* Wq        = (const float*)d_in[3];
    const float* Wk        = (const float*)d_in[4];
    const float* Wv        = (const float*)d_in[5];
    const float* Wo        = (const float*)d_in[6];
    const float* attn_n2   = (const float*)d_in[7];
    const float* ffn_w1    = (const float*)d_in[8];
    const float* ffn_b1    = (const float*)d_in[9];
    const float* ffn_w2    = (const float*)d_in[10];
    const float* ffn_b2    = (const float*)d_in[11];
    const float* ssm_norm  = (const float*)d_in[12];
    const float* in_proj   = (const float*)d_in[13];
    const float* conv_w    = (const float*)d_in[14];
    const float* conv_b    = (const float*)d_in[15];
    const float* dt_bias   = (const float*)d_in[16];
    const float* A_log     = (const float*)d_in[17];
    const float* D_skip    = (const float*)d_in[18];
    const float* mamba_nw  = (const float*)d_in[19];
    const float* out_proj  = (const float*)d_in[20];
    const float* proj_w    = (const float*)d_in[21];
    const float* proj_b    = (const float*)d_in[22];

    float* out  = (float*)d_out;
    float* Z    = out;            // z residual in out[0:HALF], dead before final GEMM
    float* P    = out + HALF;     // attention residual, dead before h_last written
    float* hout = out + HALF;

    __hip_bfloat16* wb = (__hip_bfloat16*)d_ws;
    long wo = 0;
    auto walloc = [&](long els) { __hip_bfloat16* p = wb + wo; wo += els; return p; };
    __hip_bfloat16* WqkvT = walloc(4L * 2304 * 768);
    __hip_bfloat16* W1T   = walloc(4L * 3072 * 768);
    __hip_bfloat16* W2T   = walloc(4L * 768 * 3072);
    __hip_bfloat16* inT   = walloc(4L * 3328 * 768);
    __hip_bfloat16* outT  = walloc(4L * 768 * 1536);
    __hip_bfloat16* projT = walloc(768L * 768);
    __hip_bfloat16* WoT   = walloc(4L * 768 * 768);
    char* pbase = (char*)(wb + ((wo + 255) & ~255L));
    const size_t used_w = (size_t)(pbase - (char*)d_ws);
    const size_t avail = ws_size > used_w ? ws_size - used_w : 0;

    int CB = 512;
    while (CB > 8 && (unsigned long long)CB * 884736ull > avail) CB >>= 1;
    int CBT = 256;
    while (CBT > 2 && (unsigned long long)CBT * 1912832ull > avail) CBT >>= 1;

    auto gemm = [&](const __hip_bfloat16* A, const __hip_bfloat16* BT, const float* bias,
                    void* C, int ldc, int M, int N, int Npad, int K, int flags, int moff) {
        dim3 g(Npad / 128, M / 128);
        hipLaunchKernelGGL(gemm_bf16, g, dim3(256), 0, stream,
                           A, BT, bias, C, ldc, M, N, K, flags, moff);
    };
    auto cvtT = [&](const float* W, __hip_bfloat16* WT, int K, int N, int Npad) {
        dim3 g((Npad + 31) / 32, (K + 31) / 32);
        hipLaunchKernelGGL(convT_kernel, g, dim3(256), 0, stream, W, WT, K, N, Npad);
    };
    auto cvt = [&](const float* x, __hip_bfloat16* y, long n) {
        long n4 = n / 4;
        hipLaunchKernelGGL(cvt_kernel, dim3((n4 + 255) / 256), dim3(256), 0, stream,
                           (const float4*)x, (ushort4*)y, n4);
    };
    auto rmsF = [&](const float* x, const float* w, __hip_bfloat16* o, int D, int xs, int os, long rows) {
        hipLaunchKernelGGL(rmsnorm_f32, dim3((rows + 3) / 4), dim3(256), 0, stream,
                           x, w, o, D, xs, os, rows);
    };
    auto rmsB = [&](const __hip_bfloat16* x, const float* w, __hip_bfloat16* o, int D, int xs, int os, long rows) {
        hipLaunchKernelGGL(rmsnorm_b16, dim3((rows + 3) / 4), dim3(256), 0, stream,
                           x, w, o, D, xs, os, rows);
    };

    // ---- weight conversion ----
    for (int l = 0; l < 4; l++) {
        cvtT(Wq + (long)l * 589824, WqkvT + (long)l * 2304 * 768,                768, 768, 768);
        cvtT(Wk + (long)l * 589824, WqkvT + (long)l * 2304 * 768 +  768L * 768,  768, 768, 768);
        cvtT(Wv + (long)l * 589824, WqkvT + (long)l * 2304 * 768 + 1536L * 768,  768, 768, 768);
        cvtT(Wo + (long)l * 589824, WoT + (long)l * 589824, 768, 768, 768);
        cvtT(ffn_w1 + (long)l * 2359296, W1T + (long)l * 2359296, 768, 3072, 3072);
        cvtT(ffn_w2 + (long)l * 2359296, W2T + (long)l * 2359296, 3072, 768, 768);
    }
    for (int m = 0; m < 4; m++) {
        cvtT(in_proj + (long)m * 768 * 3224, inT + (long)m * 3328 * 768, 768, 3224, 3328);
        cvtT(out_proj + (long)m * 1536 * 768, outT + (long)m * 768 * 1536, 1536, 768, 768);
    }
    cvtT(proj_w, projT, 768, 768, 768);

    // ---- attention stack ----
    hipMemcpyAsync(P, precepts, HALF * sizeof(float), hipMemcpyDeviceToDevice, stream);
    {
        const long rA = (long)CB * 64;
        __hip_bfloat16* bufA   = (__hip_bfloat16*)pbase;        // rA x 768
        __hip_bfloat16* actB   = bufA + rA * 768;               // rA x 768
        __hip_bfloat16* bufQKV = actB + rA * 768;               // rA x 2304
        __hip_bfloat16* bufH   = bufQKV + rA * 2304;            // rA x 3072
        const int nac = 512 / CB;
        const int Mr = (int)rA;
        if (nac == 1) cvt(actions, actB, rA * 768);
        for (int layer = 0; layer < 4; layer++) {
            const bool cross = ((layer + 1) % 2) == 0;
            for (int c = 0; c < nac; c++) {
                const long tok0 = (long)c * rA;
                float* Pc = P + tok0 * 768;
                rmsF(Pc, attn_n1 + layer * 768, bufA, 768, 768, 768, Mr);
                if (!cross) {
                    gemm(bufA, WqkvT + (long)layer * 2304 * 768, nullptr, bufQKV, 2304,
                         Mr, 2304, 2304, 768, FLAG_BF16, 0);
                } else {
                    if (nac != 1) cvt(actions + tok0 * 768, actB, rA * 768);
                    gemm(bufA, WqkvT + (long)layer * 2304 * 768, nullptr, bufQKV, 2304,
                         Mr, 768, 768, 768, FLAG_BF16, 0);
                    gemm(actB, WqkvT + (long)layer * 2304 * 768 + 768L * 768, nullptr,
                         bufQKV + 768, 2304, Mr, 1536, 1536, 768, FLAG_BF16, 0);
                }
                hipLaunchKernelGGL(attn_kernel, dim3(CB * 8), dim3(256), 0, stream,
                                   bufQKV, bufA);
                gemm(bufA, WoT + (long)layer * 589824, nullptr, Pc, 768,
                     Mr, 768, 768, 768, FLAG_ACC, 0);
                rmsF(Pc, attn_n2 + layer * 768, bufA, 768, 768, 768, Mr);
                gemm(bufA, W1T + (long)layer * 2359296, ffn_b1 + layer * 3072, bufH, 3072,
                     Mr, 3072, 3072, 768, FLAG_GELU | FLAG_BF16, 0);
                gemm(bufH, W2T + (long)layer * 2359296, ffn_b2 + layer * 768, Pc, 768,
                     Mr, 768, 768, 3072, FLAG_ACC, 0);
            }
        }
    }

    // ---- transpose to SSM layout ----
    hipLaunchKernelGGL(transpose_kernel, dim3((int)((HALF + 255) / 256)), dim3(256), 0, stream, P, Z);

    // ---- mamba blocks ----
    {
        const long rM = (long)CBT * 128;
        __hip_bfloat16* xn  = (__hip_bfloat16*)pbase;            // rM x 768
        __hip_bfloat16* zx  = xn + rM * 768;                     // rM x 3328
        float*          dtf = (float*)(zx + rM * 3328);          // rM x 24
        __hip_bfloat16* xc  = (__hip_bfloat16*)(dtf + rM * 24);  // rM x 1664
        __hip_bfloat16* yb  = xc + rM * 1664;                    // rM x 1536
        __hip_bfloat16* bcB = yb + rM * 1536;                    // rM x 128
        const int nmc = 256 / CBT;
        const int Mr = (int)rM;
        for (int m = 0; m < 4; m++) {
            for (int c = 0; c < nmc; c++) {
                float* Zc = Z + (long)c * rM * 768;
                rmsF(Zc, ssm_norm + m * 768, xn, 768, 768, 768, Mr);
                gemm(xn, inT + (long)m * 3328 * 768, nullptr, zx, 3328,
                     Mr, 3224, 3328, 768, FLAG_BF16, 0);
                const long convn = rM * 1664;
                hipLaunchKernelGGL(conv_kernel, dim3((int)((convn + 255) / 256)), dim3(256), 0, stream,
                                   zx, conv_w + m * 4 * 1664, conv_b + m * 1664, xc, bcB, rM);
                const long dtn = rM * 24;
                hipLaunchKernelGGL(dt_kernel, dim3((int)((dtn + 255) / 256)), dim3(256), 0, stream,
                                   zx, dt_bias + m * 24, dtf, dtn);
                hipLaunchKernelGGL(ssd_kernel, dim3(CBT * 24), dim3(256), 0, stream,
                                   zx, dtf, bcB, xc, A_log + m * 24, D_skip + m * 24,
                                   (m == 3) ? hout : nullptr, c * CBT);
                rmsB(xc, mamba_nw + m * 1536, yb, 1536, 1664, 1536, Mr);
                gemm(yb, outT + (long)m * 768 * 1536, nullptr, Zc, 768,
                     Mr, 768, 768, 1536, FLAG_ACC, 0);
            }
        }
    }

    // ---- final projection ----
    {
        __hip_bfloat16* Zb = (__hip_bfloat16*)pbase;
        cvt(Z, Zb, HALF);
        gemm(Zb, projT, proj_b, out, 768, 32768, 768, 768, 768, FLAG_PERM, 0);
    }
}

// Round 8
// 7089.691 us; speedup vs baseline: 1.4734x; 1.1311x over previous
//
#include <hip/hip_runtime.h>
#include <hip/hip_bf16.h>
#include <math.h>

// ---------------- model dims ----------------
constexpr long TOK  = 32768;            // B*N*T
constexpr long HALF = TOK * 768;
constexpr int FLAG_ACC = 1, FLAG_GELU = 2, FLAG_PERM = 4, FLAG_BF16 = 8;

typedef __bf16 bf16x8 __attribute__((ext_vector_type(8)));
typedef __bf16 bf16x4 __attribute__((ext_vector_type(4)));
typedef float  f32x4  __attribute__((ext_vector_type(4)));

__device__ __forceinline__ void gload_lds16(const void* g, void* l) {
    __builtin_amdgcn_global_load_lds(
        (const __attribute__((address_space(1))) void*)g,
        (__attribute__((address_space(3))) void*)l, 16, 0, 0);
}
__device__ __forceinline__ float bf2f(__hip_bfloat16 v) { return __bfloat162float(v); }

// ---------------- bf16 MFMA GEMM: 128x128 tile, 2-phase dbuf, vector epilogue ----
__global__ __launch_bounds__(256) void gemm_bf16(
    const __hip_bfloat16* __restrict__ A,
    const __hip_bfloat16* __restrict__ BT,
    const float* __restrict__ bias,
    void* __restrict__ Cv, int ldc,
    int M, int N, int K, int flags, int moff)
{
    __shared__ __hip_bfloat16 As[2][128 * 32];
    __shared__ __hip_bfloat16 Bs[2][128 * 32];
    const int tid = threadIdx.x;
    const int wv = tid >> 6, lane = tid & 63;
    const int nwg = gridDim.x * gridDim.y;
    const int orig = blockIdx.y * gridDim.x + blockIdx.x;
    const int q8 = nwg >> 3, r8 = nwg & 7;
    const int xcd = orig & 7, off = orig >> 3;
    const int wgid = (xcd < r8 ? xcd * (q8 + 1) : r8 * (q8 + 1) + (xcd - r8) * q8) + off;
    const int bm = (wgid / gridDim.x) * 128, bn = (wgid % gridDim.x) * 128;
    const int wr = (wv >> 1) * 64, wc = (wv & 1) * 64;
    const int lrow = lane & 15, lk = lane >> 4;
    const int ck = (lk ^ (lrow & 3) ^ ((lrow >> 2) & 3)) * 8;

    f32x4 acc[4][4];   // [n][m]
#pragma unroll
    for (int n = 0; n < 4; n++)
#pragma unroll
        for (int m = 0; m < 4; m++) acc[n][m] = f32x4{0.f, 0.f, 0.f, 0.f};

    const int nk = K >> 5;
    auto stage = [&](int kt, int buf) {
#pragma unroll
        for (int i = 0; i < 2; i++) {
            const int lin = i * 256 + tid;
            const int row = lin >> 2;
            const int ks  = (((lin & 3) ^ (row & 3) ^ ((row >> 2) & 3)) * 8);
            const long asrc = (long)(bm + row) * K + kt * 32 + ks;
            const long bsrc = (long)(bn + row) * K + kt * 32 + ks;
            char* la = (char*)&As[buf][0] + (i * 256 + wv * 64) * 16;
            char* lb = (char*)&Bs[buf][0] + (i * 256 + wv * 64) * 16;
            gload_lds16(A + asrc, la);
            gload_lds16(BT + bsrc, lb);
        }
    };

    stage(0, 0);
    __syncthreads();
    for (int kt = 0; kt < nk; kt++) {
        const int cur = kt & 1;
        if (kt + 1 < nk) stage(kt + 1, cur ^ 1);
        bf16x8 af[4], bfr[4];
#pragma unroll
        for (int m = 0; m < 4; m++) {
            af[m]  = *(const bf16x8*)(const void*)&As[cur][(wr + m * 16 + lrow) * 32 + ck];
            bfr[m] = *(const bf16x8*)(const void*)&Bs[cur][(wc + m * 16 + lrow) * 32 + ck];
        }
#pragma unroll
        for (int n = 0; n < 4; n++)
#pragma unroll
            for (int m = 0; m < 4; m++)
                acc[n][m] = __builtin_amdgcn_mfma_f32_16x16x32_bf16(bfr[n], af[m], acc[n][m], 0, 0, 0);
        __syncthreads();
    }

    float* Cf = (float*)Cv;
    __hip_bfloat16* Cb = (__hip_bfloat16*)Cv;
#pragma unroll
    for (int n = 0; n < 4; n++) {
        const int gcb = bn + wc + n * 16 + lk * 4;
        f32x4 b4 = f32x4{0.f, 0.f, 0.f, 0.f};
        if (bias) b4 = *(const f32x4*)&bias[gcb];
#pragma unroll
        for (int m = 0; m < 4; m++) {
            const int gr = bm + wr + m * 16 + lrow;
            f32x4 v = acc[n][m] + b4;
            if (flags & FLAG_GELU) {
#pragma unroll
                for (int j = 0; j < 4; j++) {
                    const float x = v[j];
                    const float u = 1.5957691216057308f * (x + 0.044715f * x * x * x);
                    v[j] = x / (1.f + __expf(-u));
                }
            }
            if (flags & FLAG_PERM) {
                const int mg = moff + gr;
                const int b_ = mg >> 13, t_ = (mg >> 7) & 63, n_ = mg & 127;
                *(f32x4*)&Cf[(((long)(b_ * 128 + n_)) * 64 + t_) * ldc + gcb] = v;
            } else if (flags & FLAG_BF16) {
                __hip_bfloat16 o0 = __float2bfloat16(v[0]), o1 = __float2bfloat16(v[1]);
                __hip_bfloat16 o2 = __float2bfloat16(v[2]), o3 = __float2bfloat16(v[3]);
                ushort4 o = { *(ushort*)&o0, *(ushort*)&o1, *(ushort*)&o2, *(ushort*)&o3 };
                *(ushort4*)&Cb[(long)gr * ldc + gcb] = o;
            } else if (flags & FLAG_ACC) {
                float* dst = &Cf[(long)gr * ldc + gcb];
                f32x4 old = *(const f32x4*)dst;
                *(f32x4*)dst = old + v;
            } else {
                *(f32x4*)&Cf[(long)gr * ldc + gcb] = v;
            }
        }
    }
}

// ---------------- weight transpose-convert: W (KxN f32) -> WT (Npad x K bf16) ----
__global__ void convT_kernel(const float* __restrict__ W, __hip_bfloat16* __restrict__ WT,
                             int K, int N, int Npad)
{
    __shared__ float t[32][33];
    const int k0 = blockIdx.y * 32, n0 = blockIdx.x * 32;
    const int tx = threadIdx.x & 31, ty = threadIdx.x >> 5;
#pragma unroll
    for (int i = 0; i < 4; i++) {
        int k = k0 + ty + i * 8, n = n0 + tx;
        t[ty + i * 8][tx] = (k < K && n < N) ? W[(long)k * N + n] : 0.f;
    }
    __syncthreads();
#pragma unroll
    for (int i = 0; i < 4; i++) {
        int n = n0 + ty + i * 8, k = k0 + tx;
        if (n < Npad && k < K) WT[(long)n * K + k] = __float2bfloat16(t[tx][ty + i * 8]);
    }
}

// ---------------- f32 -> bf16 elementwise ----------------
__global__ void cvt_kernel(const float4* __restrict__ x, ushort4* __restrict__ y, long n4)
{
    long i = (long)blockIdx.x * 256 + threadIdx.x;
    if (i >= n4) return;
    float4 v = x[i];
    __hip_bfloat16 a = __float2bfloat16(v.x), b = __float2bfloat16(v.y);
    __hip_bfloat16 c = __float2bfloat16(v.z), d = __float2bfloat16(v.w);
    ushort4 o = { *(ushort*)&a, *(ushort*)&b, *(ushort*)&c, *(ushort*)&d };
    y[i] = o;
}

// ---------------- RMSNorm, wave-per-row, vectorized (D % 256 == 0) --------------
__global__ void rmsnorm_f32(const float* __restrict__ x, const float* __restrict__ w,
                            __hip_bfloat16* __restrict__ out, int D, int xs, int os, long nrows)
{
    const int wv = threadIdx.x >> 6, lane = threadIdx.x & 63;
    const long row = (long)blockIdx.x * 4 + wv;
    if (row >= nrows) return;
    const float* xr = x + row * xs;
    const int it = D >> 8;
    float ss = 0.f;
    for (int i = 0; i < it; i++) {
        const float4 v = *(const float4*)&xr[(i * 64 + lane) * 4];
        ss += v.x * v.x + v.y * v.y + v.z * v.z + v.w * v.w;
    }
    for (int o = 32; o; o >>= 1) ss += __shfl_xor(ss, o);
    const float sc = rsqrtf(ss / D + 1e-5f);
    __hip_bfloat16* orow = out + row * os;
    for (int i = 0; i < it; i++) {
        const int e = (i * 64 + lane) * 4;
        const float4 v = *(const float4*)&xr[e];
        const float4 g = *(const float4*)&w[e];
        bf16x4 o;
        o[0] = (__bf16)(v.x * sc * g.x); o[1] = (__bf16)(v.y * sc * g.y);
        o[2] = (__bf16)(v.z * sc * g.z); o[3] = (__bf16)(v.w * sc * g.w);
        *(bf16x4*)(void*)&orow[e] = o;
    }
}
__global__ void rmsnorm_b16(const __hip_bfloat16* __restrict__ x, const float* __restrict__ w,
                            __hip_bfloat16* __restrict__ out, int D, int xs, int os, long nrows)
{
    const int wv = threadIdx.x >> 6, lane = threadIdx.x & 63;
    const long row = (long)blockIdx.x * 4 + wv;
    if (row >= nrows) return;
    const __hip_bfloat16* xr = x + row * xs;
    const int it = D >> 8;
    float ss = 0.f;
    for (int i = 0; i < it; i++) {
        const bf16x4 v = *(const bf16x4*)(const void*)&xr[(i * 64 + lane) * 4];
#pragma unroll
        for (int e = 0; e < 4; e++) { const float f = (float)v[e]; ss += f * f; }
    }
    for (int o = 32; o; o >>= 1) ss += __shfl_xor(ss, o);
    const float sc = rsqrtf(ss / D + 1e-5f);
    __hip_bfloat16* orow = out + row * os;
    for (int i = 0; i < it; i++) {
        const int e = (i * 64 + lane) * 4;
        const bf16x4 v = *(const bf16x4*)(const void*)&xr[e];
        const float4 g = *(const float4*)&w[e];
        bf16x4 o;
        o[0] = (__bf16)((float)v[0] * sc * g.x); o[1] = (__bf16)((float)v[1] * sc * g.y);
        o[2] = (__bf16)((float)v[2] * sc * g.z); o[3] = (__bf16)((float)v[3] * sc * g.w);
        *(bf16x4*)(void*)&orow[e] = o;
    }
}

// ---------------- fused attention, MFMA version: block per (batch, head) --------
// QKV: [64 x 2304] bf16 per batch (Q|K|V). O: [64 x 768] bf16.
__global__ __launch_bounds__(256) void attn_kernel(
    const __hip_bfloat16* __restrict__ QKV, __hip_bfloat16* __restrict__ O)
{
    __shared__ __align__(16) __hip_bfloat16 Qs[3 * 64 * 32];   // 12KB [kst][q][32]
    __shared__ __align__(16) __hip_bfloat16 Ks[3 * 64 * 32];   // 12KB [kst][k][32]
    __shared__ __align__(16) __hip_bfloat16 VT[2 * 96 * 32];   // 12KB [kst][d][32]
    __shared__ __align__(16) __hip_bfloat16 Ps[2 * 64 * 32];   //  8KB [kst][q][32]
    const int tid = threadIdx.x;
    const int wid = tid >> 6, lane = tid & 63;
    const int lrow = lane & 15, lk = lane >> 4;
    const int b = blockIdx.x >> 3, h = blockIdx.x & 7;
    const long base = (long)b * 64 * 2304 + h * 96;

    // stage Q,K (XOR-chunk layout, 96 = 3 chunks of 32)
#pragma unroll
    for (int i = 0; i < 3; i++) {
        const int v = i * 256 + tid;              // 0..767 = 64 rows x 12 chunks
        const int r = v / 12, c8 = v - r * 12;
        const int kst = c8 >> 2, ch = c8 & 3, slot = ch ^ (r & 3);
        const bf16x8 q = *(const bf16x8*)(const void*)&QKV[base + (long)r * 2304 + c8 * 8];
        const bf16x8 k = *(const bf16x8*)(const void*)&QKV[base + (long)r * 2304 + 768 + c8 * 8];
        *(bf16x8*)(void*)&Qs[(kst * 64 + r) * 32 + slot * 8] = q;
        *(bf16x8*)(void*)&Ks[(kst * 64 + r) * 32 + slot * 8] = k;
    }
    // stage V^T: [d][k] (k = 2 chunks of 32); wave wid covers k = wid*16..+15
    for (int i = 0; i < 16; i++) {
        const int k = wid * 16 + i;
        const __hip_bfloat16* vrow = &QKV[base + (long)k * 2304 + 1536];
        const int sb = (k >> 3) & 3, khi = k >> 5, klo = k & 7;
        {
            const int d = lane;
            VT[(khi * 96 + d) * 32 + ((sb ^ (d & 3)) * 8) + klo] = vrow[d];
        }
        if (lane < 32) {
            const int d = 64 + lane;
            VT[(khi * 96 + d) * 32 + ((sb ^ (d & 3)) * 8) + klo] = vrow[d];
        }
    }
    __syncthreads();

    // QK^T: wave wid owns q rows wid*16..+15; S[q][k] for all 64 k
    const int ck = (lk ^ (lrow & 3)) * 8;
    f32x4 s[4];
#pragma unroll
    for (int n = 0; n < 4; n++) s[n] = f32x4{0.f, 0.f, 0.f, 0.f};
#pragma unroll
    for (int kst = 0; kst < 3; kst++) {
        const bf16x8 qf = *(const bf16x8*)(const void*)&Qs[(kst * 64 + wid * 16 + lrow) * 32 + ck];
#pragma unroll
        for (int n = 0; n < 4; n++) {
            const bf16x8 kf = *(const bf16x8*)(const void*)&Ks[(kst * 64 + n * 16 + lrow) * 32 + ck];
            s[n] = __builtin_amdgcn_mfma_f32_16x16x32_bf16(qf, kf, s[n], 0, 0, 0);
        }
    }
    // softmax: lane holds S[q = wid*16 + lk*4 + j][k = n*16 + lrow]
    const float scale = 0.102062072615966f;   // 1/sqrt(96)
#pragma unroll
    for (int n = 0; n < 4; n++) s[n] *= scale;
    float inv[4];
#pragma unroll
    for (int j = 0; j < 4; j++) {
        float mx = fmaxf(fmaxf(s[0][j], s[1][j]), fmaxf(s[2][j], s[3][j]));
        mx = fmaxf(mx, __shfl_xor(mx, 1));
        mx = fmaxf(mx, __shfl_xor(mx, 2));
        mx = fmaxf(mx, __shfl_xor(mx, 4));
        mx = fmaxf(mx, __shfl_xor(mx, 8));
        float sum = 0.f;
#pragma unroll
        for (int n = 0; n < 4; n++) { s[n][j] = __expf(s[n][j] - mx); sum += s[n][j]; }
        sum += __shfl_xor(sum, 1);
        sum += __shfl_xor(sum, 2);
        sum += __shfl_xor(sum, 4);
        sum += __shfl_xor(sum, 8);
        inv[j] = 1.f / sum;
    }
    // write P[q][k] to LDS (XOR layout)
#pragma unroll
    for (int n = 0; n < 4; n++) {
        const int k = n * 16 + lrow;
        const int kst = n >> 1, kc = ((n & 1) << 1) + (lrow >> 3), ke = lrow & 7;
#pragma unroll
        for (int j = 0; j < 4; j++) {
            const int q = wid * 16 + lk * 4 + j;
            Ps[(kst * 64 + q) * 32 + ((kc ^ (q & 3)) * 8) + ke] = __float2bfloat16(s[n][j] * inv[j]);
        }
    }
    __syncthreads();

    // PV: Y^T-ish: acc[mv][np] = mfma(VT-frag(d), P-frag(q)) -> lane: 4 consecutive d
    const int wq = wid >> 1, wd = wid & 1;
    f32x4 y[3][2];
#pragma unroll
    for (int mv = 0; mv < 3; mv++)
#pragma unroll
        for (int np = 0; np < 2; np++) y[mv][np] = f32x4{0.f, 0.f, 0.f, 0.f};
#pragma unroll
    for (int ks = 0; ks < 2; ks++) {
        bf16x8 vf[3], pf[2];
#pragma unroll
        for (int mv = 0; mv < 3; mv++)
            vf[mv] = *(const bf16x8*)(const void*)&VT[(ks * 96 + wd * 48 + mv * 16 + lrow) * 32 + ck];
#pragma unroll
        for (int np = 0; np < 2; np++)
            pf[np] = *(const bf16x8*)(const void*)&Ps[(ks * 64 + wq * 32 + np * 16 + lrow) * 32 + ck];
#pragma unroll
        for (int mv = 0; mv < 3; mv++)
#pragma unroll
            for (int np = 0; np < 2; np++)
                y[mv][np] = __builtin_amdgcn_mfma_f32_16x16x32_bf16(vf[mv], pf[np], y[mv][np], 0, 0, 0);
    }
    // store: d = wd*48 + mv*16 + lk*4 + j (4 consecutive), q = wq*32 + np*16 + lrow
#pragma unroll
    for (int mv = 0; mv < 3; mv++) {
        const int d0 = wd * 48 + mv * 16 + lk * 4;
#pragma unroll
        for (int np = 0; np < 2; np++) {
            const int q = wq * 32 + np * 16 + lrow;
            bf16x4 o;
#pragma unroll
            for (int j = 0; j < 4; j++) o[j] = (__bf16)y[mv][np][j];
            *(bf16x4*)(void*)&O[(long)(b * 64 + q) * 768 + h * 96 + d0] = o;
        }
    }
}

// ---------------- transpose p (B,N,T,D) -> z (B,T,N,D) ----------------
__global__ void transpose_kernel(const float* __restrict__ P, float* __restrict__ Z)
{
    long lin = (long)blockIdx.x * 256 + threadIdx.x;
    if (lin >= HALF) return;
    int d = (int)(lin % 768);
    long rowz = lin / 768;
    int n = rowz & 127, t = (int)((rowz >> 7) & 63), b = (int)(rowz >> 13);
    long rowp = ((long)(b * 128 + n)) * 64 + t;
    Z[lin] = P[rowp * 768 + d];
}

// -------- causal depthwise conv + SiLU, vectorized: block per row, 8 chan/thread
__global__ __launch_bounds__(256) void conv_kernel(
    const __hip_bfloat16* __restrict__ zx, const float* __restrict__ cw,
    const float* __restrict__ cb, __hip_bfloat16* __restrict__ xc,
    __hip_bfloat16* __restrict__ bcB, long rows)
{
    const long r = blockIdx.x;
    const int tid = threadIdx.x;
    if (tid >= 208) return;
    const int c0 = tid * 8;
    const int n = (int)(r & 127);
    float acc[8];
    {
        const float4 b0 = *(const float4*)&cb[c0];
        const float4 b1 = *(const float4*)&cb[c0 + 4];
        acc[0] = b0.x; acc[1] = b0.y; acc[2] = b0.z; acc[3] = b0.w;
        acc[4] = b1.x; acc[5] = b1.y; acc[6] = b1.z; acc[7] = b1.w;
    }
#pragma unroll
    for (int k = 0; k < 4; k++) {
        if (n - 3 + k < 0) continue;
        const bf16x8 xv = *(const bf16x8*)(const void*)&zx[(r - 3 + k) * 3328 + 1536 + c0];
        const float4 w0 = *(const float4*)&cw[k * 1664 + c0];
        const float4 w1 = *(const float4*)&cw[k * 1664 + c0 + 4];
        acc[0] += w0.x * (float)xv[0]; acc[1] += w0.y * (float)xv[1];
        acc[2] += w0.z * (float)xv[2]; acc[3] += w0.w * (float)xv[3];
        acc[4] += w1.x * (float)xv[4]; acc[5] += w1.y * (float)xv[5];
        acc[6] += w1.z * (float)xv[6]; acc[7] += w1.w * (float)xv[7];
    }
    bf16x8 o;
#pragma unroll
    for (int e = 0; e < 8; e++) {
        const float s = acc[e] / (1.f + __expf(-acc[e]));
        o[e] = (__bf16)s;
    }
    if (c0 < 1536) *(bf16x8*)(void*)&xc[r * 1664 + c0] = o;
    else           *(bf16x8*)(void*)&bcB[r * 128 + (c0 - 1536)] = o;
}

// ---------------- dt = softplus(dt_raw + bias) -> f32 side buffer ----------------
__global__ void dt_kernel(const __hip_bfloat16* __restrict__ zx, const float* __restrict__ bias,
                          float* __restrict__ dtf, long count)
{
    long lin = (long)blockIdx.x * 256 + threadIdx.x;
    if (lin >= count) return;
    int h = (int)(lin % 24);
    long r = lin / 24;
    float v = bf2f(zx[r * 3328 + 3200 + h]) + bias[h];
    dtf[lin] = (v > 0.f) ? v + log1pf(expf(-v)) : log1pf(expf(v));
}

// ======== SSD (chunked-scan) kernel: block per (bt, h); MFMA everywhere ========
__global__ __launch_bounds__(256) void ssd_kernel(
    const __hip_bfloat16* __restrict__ zx0, const float* __restrict__ dtf0,
    const __hip_bfloat16* __restrict__ bcB0, __hip_bfloat16* __restrict__ xc0,
    const float* __restrict__ Alog, const float* __restrict__ Dskip,
    float* __restrict__ hout, int bt0)
{
    __shared__ __align__(16) char SM[50688];
    __hip_bfloat16* Cl  = (__hip_bfloat16*)SM;            // [2][128][32]
    __hip_bfloat16* Bl  = Cl + 8192;                      // [2][128][32]
    __hip_bfloat16* Ml  = (__hip_bfloat16*)SM;            // [4][128][32] overlays Cl+Bl
    __hip_bfloat16* XTl = (__hip_bfloat16*)(SM + 32768);  // [4][64][32]  (X^T: [p][t])
    __hip_bfloat16* BTl = (__hip_bfloat16*)SM;            // [4][64][32]  overlays Ml (hT)
    float* cum = (float*)(SM + 49152);                    // [128]
    float* dtl = cum + 128;                               // [128]
    float* wl  = dtl + 128;                               // [128]

    const int tid = threadIdx.x;
    const int wid = tid >> 6, lane = tid & 63;
    const int lrow = lane & 15, lk = lane >> 4;
    const int btl = blockIdx.x / 24, h = blockIdx.x % 24;
    const long rowbase = (long)btl * 128;

    const __hip_bfloat16* zxp = zx0 + rowbase * 3328 + h * 64;
    const float* dtp = dtf0 + rowbase * 24;
    const __hip_bfloat16* bcp = bcB0 + rowbase * 128;
    __hip_bfloat16* xcp = xc0 + rowbase * 1664 + h * 64;

    const float A  = -expf(Alog[h]);
    const float Dh = Dskip[h];

#pragma unroll
    for (int i = 0; i < 4; i++) {
        const int v = tid + i * 256;
        const int row = v >> 3, c8 = v & 7;
        const int kst = c8 >> 2, ch = c8 & 3;
        const int slot = ch ^ (row & 3);
        bf16x8 vB = *(const bf16x8*)(const void*)&bcp[(long)row * 128 + c8 * 8];
        bf16x8 vC = *(const bf16x8*)(const void*)&bcp[(long)row * 128 + 64 + c8 * 8];
        *(bf16x8*)(void*)&Bl[(kst * 128 + row) * 32 + slot * 8] = vB;
        *(bf16x8*)(void*)&Cl[(kst * 128 + row) * 32 + slot * 8] = vC;
    }
    for (int i = 0; i < 32; i++) {
        const int t = wid * 32 + i;
        const int slot = (i >> 3) ^ (lane & 3);
        XTl[(wid * 64 + lane) * 32 + slot * 8 + (i & 7)] = xcp[(long)t * 1664 + lane];
    }
    if (tid < 128) dtl[tid] = dtp[(long)tid * 24 + h];
    __syncthreads();
    if (tid < 128) cum[tid] = dtl[tid] * A;
    __syncthreads();
    for (int off = 1; off < 128; off <<= 1) {
        float v = 0.f;
        if (tid < 128 && tid >= off) v = cum[tid - off];
        __syncthreads();
        if (tid < 128) cum[tid] += v;
        __syncthreads();
    }
    if (tid < 128) wl[tid] = expf(cum[127] - cum[tid]) * dtl[tid];
    __syncthreads();

    const int wr1 = (wid >> 1) * 64, wc1 = (wid & 1) * 64;
    const int ck = (lk ^ (lrow & 3)) * 8;
    f32x4 a1[4][4];
#pragma unroll
    for (int m = 0; m < 4; m++)
#pragma unroll
        for (int n = 0; n < 4; n++) a1[m][n] = f32x4{0.f, 0.f, 0.f, 0.f};
#pragma unroll
    for (int kst = 0; kst < 2; kst++) {
        bf16x8 ca[4], bb[4];
#pragma unroll
        for (int m = 0; m < 4; m++)
            ca[m] = *(const bf16x8*)(const void*)&Cl[(kst * 128 + wr1 + m * 16 + lrow) * 32 + ck];
#pragma unroll
        for (int n = 0; n < 4; n++)
            bb[n] = *(const bf16x8*)(const void*)&Bl[(kst * 128 + wc1 + n * 16 + lrow) * 32 + ck];
#pragma unroll
        for (int m = 0; m < 4; m++)
#pragma unroll
            for (int n = 0; n < 4; n++)
                a1[m][n] = __builtin_amdgcn_mfma_f32_16x16x32_bf16(ca[m], bb[n], a1[m][n], 0, 0, 0);
    }
    __syncthreads();

#pragma unroll
    for (int m = 0; m < 4; m++) {
        const int tb = wr1 + m * 16 + lk * 4;
        const f32x4 c4 = *(const f32x4*)&cum[tb];
#pragma unroll
        for (int n = 0; n < 4; n++) {
            const int j = wc1 + n * 16 + lrow;
            const float cj = cum[j], dj = dtl[j];
            const int jst = j >> 5, jc = (j >> 3) & 3, je = j & 7;
#pragma unroll
            for (int jj = 0; jj < 4; jj++) {
                const int t = tb + jj;
                float val = 0.f;
                if (j <= t) val = a1[m][n][jj] * expf(c4[jj] - cj) * dj;
                Ml[(jst * 128 + t) * 32 + ((jc ^ (t & 3)) * 8) + je] = __float2bfloat16(val);
            }
        }
    }
    __syncthreads();

    const int wr2 = (wid >> 1) * 64, wc2 = (wid & 1) * 32;
    f32x4 a2[4][2];
#pragma unroll
    for (int m = 0; m < 4; m++)
#pragma unroll
        for (int n = 0; n < 2; n++) a2[m][n] = f32x4{0.f, 0.f, 0.f, 0.f};
#pragma unroll
    for (int kst = 0; kst < 4; kst++) {
        bf16x8 am[4], bn[2];
#pragma unroll
        for (int m = 0; m < 4; m++)
            am[m] = *(const bf16x8*)(const void*)&Ml[(kst * 128 + wr2 + m * 16 + lrow) * 32 + ck];
#pragma unroll
        for (int n = 0; n < 2; n++)
            bn[n] = *(const bf16x8*)(const void*)&XTl[(kst * 64 + wc2 + n * 16 + lrow) * 32 + ck];
#pragma unroll
        for (int m = 0; m < 4; m++)
#pragma unroll
            for (int n = 0; n < 2; n++)
                a2[m][n] = __builtin_amdgcn_mfma_f32_16x16x32_bf16(am[m], bn[n], a2[m][n], 0, 0, 0);
    }

#pragma unroll
    for (int m = 0; m < 4; m++) {
        const int tb = wr2 + m * 16 + lk * 4;
#pragma unroll
        for (int n = 0; n < 2; n++) {
            const int p = wc2 + n * 16 + lrow;
#pragma unroll
            for (int jj = 0; jj < 4; jj++) {
                const int t = tb + jj;
                const float x = bf2f(XTl[((t >> 5) * 64 + p) * 32 + ((((t >> 3) & 3) ^ (p & 3)) * 8) + (t & 7)]);
                const float zg = bf2f(zxp[(long)t * 3328 + p]);
                const float y = (a2[m][n][jj] + Dh * x) * (zg / (1.f + expf(-zg)));
                xcp[(long)t * 1664 + p] = __float2bfloat16(y);
            }
        }
    }

    if (hout) {
        __syncthreads();
        for (int i = 0; i < 32; i++) {
            const int j = wid * 32 + i;
            const int slot = (i >> 3) ^ (lane & 3);
            BTl[(wid * 64 + lane) * 32 + slot * 8 + (j & 7)] = bcp[(long)j * 128 + lane];
        }
        __syncthreads();
        const int wrp = (wid >> 1) * 32, wcs = (wid & 1) * 32;
        f32x4 a3[2][2];
#pragma unroll
        for (int m = 0; m < 2; m++)
#pragma unroll
            for (int n = 0; n < 2; n++) a3[m][n] = f32x4{0.f, 0.f, 0.f, 0.f};
#pragma unroll
        for (int kst = 0; kst < 4; kst++) {
            const int jb = kst * 32 + lk * 8;
            const f32x4 wa = *(const f32x4*)&wl[jb];
            const f32x4 wb = *(const f32x4*)&wl[jb + 4];
            bf16x8 xw[2], bn[2];
#pragma unroll
            for (int m = 0; m < 2; m++) {
                bf16x8 xr = *(const bf16x8*)(const void*)&XTl[(kst * 64 + wrp + m * 16 + lrow) * 32 + ck];
                bf16x8 t;
#pragma unroll
                for (int e = 0; e < 4; e++) t[e] = (__bf16)((float)xr[e] * wa[e]);
#pragma unroll
                for (int e = 0; e < 4; e++) t[4 + e] = (__bf16)((float)xr[4 + e] * wb[e]);
                xw[m] = t;
            }
#pragma unroll
            for (int n = 0; n < 2; n++)
                bn[n] = *(const bf16x8*)(const void*)&BTl[(kst * 64 + wcs + n * 16 + lrow) * 32 + ck];
#pragma unroll
            for (int m = 0; m < 2; m++)
#pragma unroll
                for (int n = 0; n < 2; n++)
                    a3[m][n] = __builtin_amdgcn_mfma_f32_16x16x32_bf16(xw[m], bn[n], a3[m][n], 0, 0, 0);
        }
        float* hp = hout + ((long)(bt0 + btl) * 24 + h) * 4096;
#pragma unroll
        for (int m = 0; m < 2; m++) {
            const int pb = wrp + m * 16 + lk * 4;
#pragma unroll
            for (int n = 0; n < 2; n++) {
                const int s = wcs + n * 16 + lrow;
#pragma unroll
                for (int jj = 0; jj < 4; jj++)
                    hp[(long)(pb + jj) * 64 + s] = a3[m][n][jj];
            }
        }
    }
}

// ---------------- host orchestration ----------------
extern "C" void kernel_launch(void* const* d_in, const int* in_sizes, int n_in,
                              void* d_out, int out_size, void* d_ws, size_t ws_size,
                              hipStream_t stream)
{
    const float* precepts  = (const float*)d_in[0];
    const float* actions   = (const float*)d_in[1];
    const float* attn_n1   = (const float*)d_in[2];
    const float* Wq        = (const float*)d_in[3];
    const float* Wk        = (const float*)d_in[4];
    const float* Wv        = (const float*)d_in[5];
    const float* Wo        = (const float*)d_in[6];
    const float* attn_n2   = (const float*)d_in[7];
    const float* ffn_w1    = (const float*)d_in[8];
    const float* ffn_b1    = (const float*)d_in[9];
    const float* ffn_w2    = (const float*)d_in[10];
    const float* ffn_b2    = (const float*)d_in[11];
    const float* ssm_norm  = (const float*)d_in[12];
    const float* in_proj   = (const float*)d_in[13];
    const float* conv_w    = (const float*)d_in[14];
    const float* conv_b    = (const float*)d_in[15];
    const float* dt_bias   = (const float*)d_in[16];
    const float* A_log     = (const float*)d_in[17];
    const float* D_skip    = (const float*)d_in[18];
    const float* mamba_nw  = (const float*)d_in[19];
    const float* out_proj  = (const float*)d_in[20];
    const float* proj_w    = (const float*)d_in[21];
    const float* proj_b    = (const float*)d_in[22];

    float* out  = (float*)d_out;
    float* Z    = out;            // z residual in out[0:HALF], dead before final GEMM
    float* P    = out + HALF;     // attention residual, dead before h_last written
    float* hout = out + HALF;

    __hip_bfloat16* wb = (__hip_bfloat16*)d_ws;
    long wo = 0;
    auto walloc = [&](long els) { __hip_bfloat16* p = wb + wo; wo += els; return p; };
    __hip_bfloat16* WqkvT = walloc(4L * 2304 * 768);
    __hip_bfloat16* W1T   = walloc(4L * 3072 * 768);
    __hip_bfloat16* W2T   = walloc(4L * 768 * 3072);
    __hip_bfloat16* inT   = walloc(4L * 3328 * 768);
    __hip_bfloat16* outT  = walloc(4L * 768 * 1536);
    __hip_bfloat16* projT = walloc(768L * 768);
    __hip_bfloat16* WoT   = walloc(4L * 768 * 768);
    char* pbase = (char*)(wb + ((wo + 255) & ~255L));
    const size_t used_w = (size_t)(pbase - (char*)d_ws);
    const size_t avail = ws_size > used_w ? ws_size - used_w : 0;

    int CB = 512;
    while (CB > 8 && (unsigned long long)CB * 884736ull > avail) CB >>= 1;
    int CBT = 256;
    while (CBT > 2 && (unsigned long long)CBT * 1912832ull > avail) CBT >>= 1;

    auto gemm = [&](const __hip_bfloat16* A, const __hip_bfloat16* BT, const float* bias,
                    void* C, int ldc, int M, int N, int Npad, int K, int flags, int moff) {
        dim3 g(Npad / 128, M / 128);
        hipLaunchKernelGGL(gemm_bf16, g, dim3(256), 0, stream,
                           A, BT, bias, C, ldc, M, N, K, flags, moff);
    };
    auto cvtT = [&](const float* W, __hip_bfloat16* WT, int K, int N, int Npad) {
        dim3 g((Npad + 31) / 32, (K + 31) / 32);
        hipLaunchKernelGGL(convT_kernel, g, dim3(256), 0, stream, W, WT, K, N, Npad);
    };
    auto cvt = [&](const float* x, __hip_bfloat16* y, long n) {
        long n4 = n / 4;
        hipLaunchKernelGGL(cvt_kernel, dim3((n4 + 255) / 256), dim3(256), 0, stream,
                           (const float4*)x, (ushort4*)y, n4);
    };
    auto rmsF = [&](const float* x, const float* w, __hip_bfloat16* o, int D, int xs, int os, long rows) {
        hipLaunchKernelGGL(rmsnorm_f32, dim3((rows + 3) / 4), dim3(256), 0, stream,
                           x, w, o, D, xs, os, rows);
    };
    auto rmsB = [&](const __hip_bfloat16* x, const float* w, __hip_bfloat16* o, int D, int xs, int os, long rows) {
        hipLaunchKernelGGL(rmsnorm_b16, dim3((rows + 3) / 4), dim3(256), 0, stream,
                           x, w, o, D, xs, os, rows);
    };

    // ---- weight conversion ----
    for (int l = 0; l < 4; l++) {
        cvtT(Wq + (long)l * 589824, WqkvT + (long)l * 2304 * 768,                768, 768, 768);
        cvtT(Wk + (long)l * 589824, WqkvT + (long)l * 2304 * 768 +  768L * 768,  768, 768, 768);
        cvtT(Wv + (long)l * 589824, WqkvT + (long)l * 2304 * 768 + 1536L * 768,  768, 768, 768);
        cvtT(Wo + (long)l * 589824, WoT + (long)l * 589824, 768, 768, 768);
        cvtT(ffn_w1 + (long)l * 2359296, W1T + (long)l * 2359296, 768, 3072, 3072);
        cvtT(ffn_w2 + (long)l * 2359296, W2T + (long)l * 2359296, 3072, 768, 768);
    }
    for (int m = 0; m < 4; m++) {
        cvtT(in_proj + (long)m * 768 * 3224, inT + (long)m * 3328 * 768, 768, 3224, 3328);
        cvtT(out_proj + (long)m * 1536 * 768, outT + (long)m * 768 * 1536, 1536, 768, 768);
    }
    cvtT(proj_w, projT, 768, 768, 768);

    // ---- attention stack ----
    hipMemcpyAsync(P, precepts, HALF * sizeof(float), hipMemcpyDeviceToDevice, stream);
    {
        const long rA = (long)CB * 64;
        __hip_bfloat16* bufA   = (__hip_bfloat16*)pbase;        // rA x 768
        __hip_bfloat16* actB   = bufA + rA * 768;               // rA x 768
        __hip_bfloat16* bufQKV = actB + rA * 768;               // rA x 2304
        __hip_bfloat16* bufH   = bufQKV + rA * 2304;            // rA x 3072
        const int nac = 512 / CB;
        const int Mr = (int)rA;
        if (nac == 1) cvt(actions, actB, rA * 768);
        for (int layer = 0; layer < 4; layer++) {
            const bool cross = ((layer + 1) % 2) == 0;
            for (int c = 0; c < nac; c++) {
                const long tok0 = (long)c * rA;
                float* Pc = P + tok0 * 768;
                rmsF(Pc, attn_n1 + layer * 768, bufA, 768, 768, 768, Mr);
                if (!cross) {
                    gemm(bufA, WqkvT + (long)layer * 2304 * 768, nullptr, bufQKV, 2304,
                         Mr, 2304, 2304, 768, FLAG_BF16, 0);
                } else {
                    if (nac != 1) cvt(actions + tok0 * 768, actB, rA * 768);
                    gemm(bufA, WqkvT + (long)layer * 2304 * 768, nullptr, bufQKV, 2304,
                         Mr, 768, 768, 768, FLAG_BF16, 0);
                    gemm(actB, WqkvT + (long)layer * 2304 * 768 + 768L * 768, nullptr,
                         bufQKV + 768, 2304, Mr, 1536, 1536, 768, FLAG_BF16, 0);
                }
                hipLaunchKernelGGL(attn_kernel, dim3(CB * 8), dim3(256), 0, stream,
                                   bufQKV, bufA);
                gemm(bufA, WoT + (long)layer * 589824, nullptr, Pc, 768,
                     Mr, 768, 768, 768, FLAG_ACC, 0);
                rmsF(Pc, attn_n2 + layer * 768, bufA, 768, 768, 768, Mr);
                gemm(bufA, W1T + (long)layer * 2359296, ffn_b1 + layer * 3072, bufH, 3072,
                     Mr, 3072, 3072, 768, FLAG_GELU | FLAG_BF16, 0);
                gemm(bufH, W2T + (long)layer * 2359296, ffn_b2 + layer * 768, Pc, 768,
                     Mr, 768, 768, 3072, FLAG_ACC, 0);
            }
        }
    }

    // ---- transpose to SSM layout ----
    hipLaunchKernelGGL(transpose_kernel, dim3((int)((HALF + 255) / 256)), dim3(256), 0, stream, P, Z);

    // ---- mamba blocks ----
    {
        const long rM = (long)CBT * 128;
        __hip_bfloat16* xn  = (__hip_bfloat16*)pbase;            // rM x 768
        __hip_bfloat16* zx  = xn + rM * 768;                     // rM x 3328
        float*          dtf = (float*)(zx + rM * 3328);          // rM x 24
        __hip_bfloat16* xc  = (__hip_bfloat16*)(dtf + rM * 24);  // rM x 1664
        __hip_bfloat16* yb  = xc + rM * 1664;                    // rM x 1536
        __hip_bfloat16* bcB = yb + rM * 1536;                    // rM x 128
        const int nmc = 256 / CBT;
        const int Mr = (int)rM;
        for (int m = 0; m < 4; m++) {
            for (int c = 0; c < nmc; c++) {
                float* Zc = Z + (long)c * rM * 768;
                rmsF(Zc, ssm_norm + m * 768, xn, 768, 768, 768, Mr);
                gemm(xn, inT + (long)m * 3328 * 768, nullptr, zx, 3328,
                     Mr, 3224, 3328, 768, FLAG_BF16, 0);
                hipLaunchKernelGGL(conv_kernel, dim3((int)rM), dim3(256), 0, stream,
                                   zx, conv_w + m * 4 * 1664, conv_b + m * 1664, xc, bcB, rM);
                const long dtn = rM * 24;
                hipLaunchKernelGGL(dt_kernel, dim3((int)((dtn + 255) / 256)), dim3(256), 0, stream,
                                   zx, dt_bias + m * 24, dtf, dtn);
                hipLaunchKernelGGL(ssd_kernel, dim3(CBT * 24), dim3(256), 0, stream,
                                   zx, dtf, bcB, xc, A_log + m * 24, D_skip + m * 24,
                                   (m == 3) ? hout : nullptr, c * CBT);
                rmsB(xc, mamba_nw + m * 1536, yb, 1536, 1664, 1536, Mr);
                gemm(yb, outT + (long)m * 768 * 1536, nullptr, Zc, 768,
                     Mr, 768, 768, 1536, FLAG_ACC, 0);
            }
        }
    }

    // ---- final projection ----
    {
        __hip_bfloat16* Zb = (__hip_bfloat16*)pbase;
        cvt(Z, Zb, HALF);
        gemm(Zb, projT, proj_b, out, 768, 32768, 768, 768, 768, FLAG_PERM, 0);
    }
}